// Round 1
// baseline (424.833 us; speedup 1.0000x reference)
//
#include <hip/hip_runtime.h>
#include <cstdint>
#include <cstddef>

typedef short s16x8 __attribute__((ext_vector_type(8)));
typedef float f32x4 __attribute__((ext_vector_type(4)));

#define MFMA16(a, b, c) __builtin_amdgcn_mfma_f32_16x16x32_bf16((a), (b), (c), 0, 0, 0)

constexpr int LDP = 72;  // padded LDS row stride (bf16 elems); 144 B keeps b128 16B-aligned, 2-way bank alias (free)

__device__ __forceinline__ short f2bf(float f) {
    unsigned u = __builtin_bit_cast(unsigned, f);
    u += 0x7FFFu + ((u >> 16) & 1u);   // RNE
    return (short)(u >> 16);
}
__device__ __forceinline__ float bf2f(short s) {
    unsigned u = ((unsigned)(unsigned short)s) << 16;
    return __builtin_bit_cast(float, u);
}
__device__ __forceinline__ unsigned pack2(float a, float b) {
    return (unsigned)(unsigned short)f2bf(a) | ((unsigned)(unsigned short)f2bf(b) << 16);
}
__device__ __forceinline__ float qmax16(float v) {
    v = fmaxf(v, __shfl_xor(v, 1));
    v = fmaxf(v, __shfl_xor(v, 2));
    v = fmaxf(v, __shfl_xor(v, 4));
    v = fmaxf(v, __shfl_xor(v, 8));
    return v;
}
__device__ __forceinline__ float qsum16(float v) {
    v += __shfl_xor(v, 1);
    v += __shfl_xor(v, 2);
    v += __shfl_xor(v, 4);
    v += __shfl_xor(v, 8);
    return v;
}

// ---------------------------------------------------------------------------
// Kernel 1: QKV projection. C[m,n] = sum_k x[m,k] * W[n,k]  (NT GEMM)
// M=4096 (B*T), N=3072 (q|k|v), K=1024. Tile 64x64, BK=64, 4 waves.
// Epilogue scatters bf16 to Q/K/V in [B,H,T,D] layout (one head per block).
// ---------------------------------------------------------------------------
__global__ __launch_bounds__(256) void qkv_kernel(
    const float* __restrict__ x, const float* __restrict__ Wq,
    const float* __restrict__ Wk, const float* __restrict__ Wv,
    short* __restrict__ Qo, short* __restrict__ Ko, short* __restrict__ Vo) {
    __shared__ short sA[64 * LDP];
    __shared__ short sB[64 * LDP];
    const int tid = threadIdx.x;
    const int w = tid >> 6, lane = tid & 63, quad = lane >> 4, l15 = lane & 15;
    const int bx = blockIdx.x, by = blockIdx.y;
    const int wsel = bx >> 4;           // 0=q 1=k 2=v
    const int h = bx & 15;              // head (64 cols == one head)
    const float* W = (wsel == 0) ? Wq : ((wsel == 1) ? Wk : Wv);
    const int n0 = h * 64;
    const int m0 = by * 64;

    f32x4 acc[4];
#pragma unroll
    for (int i = 0; i < 4; i++) acc[i] = f32x4{0.f, 0.f, 0.f, 0.f};

    for (int kb = 0; kb < 16; kb++) {
        const int k0 = kb * 64;
        if (kb) __syncthreads();
#pragma unroll
        for (int i = 0; i < 4; i++) {
            int p = tid + i * 256;          // 1024 float4 slots: 64 rows x 16
            int row = p >> 4, c4 = p & 15;
            float4 av = *(const float4*)(x + (size_t)(m0 + row) * 1024 + k0 + c4 * 4);
            float4 bv = *(const float4*)(W + (size_t)(n0 + row) * 1024 + k0 + c4 * 4);
            *(uint2*)&sA[row * LDP + c4 * 4] = make_uint2(pack2(av.x, av.y), pack2(av.z, av.w));
            *(uint2*)&sB[row * LDP + c4 * 4] = make_uint2(pack2(bv.x, bv.y), pack2(bv.z, bv.w));
        }
        __syncthreads();
#pragma unroll
        for (int ks = 0; ks < 2; ks++) {
            s16x8 a = *(const s16x8*)&sA[(w * 16 + l15) * LDP + ks * 32 + quad * 8];
#pragma unroll
            for (int ct = 0; ct < 4; ct++) {
                s16x8 b = *(const s16x8*)&sB[(ct * 16 + l15) * LDP + ks * 32 + quad * 8];
                acc[ct] = MFMA16(a, b, acc[ct]);
            }
        }
    }

    short* Out = (wsel == 0) ? Qo : ((wsel == 1) ? Ko : Vo);
#pragma unroll
    for (int ct = 0; ct < 4; ct++)
#pragma unroll
        for (int r = 0; r < 4; r++) {
            int m = m0 + w * 16 + quad * 4 + r;   // global row = b*2048 + t
            int b = m >> 11, t = m & 2047;
            size_t idx = (((size_t)(b * 16 + h)) * 2048 + t) * 64 + ct * 16 + l15;
            Out[idx] = f2bf(acc[ct][r]);
        }
}

// ---------------------------------------------------------------------------
// Kernel 2: RoPE in-place on Q and K ([B,H,T,D] bf16). One thread per row.
// out[i]    = x[2i]*cos - x[2i+1]*sin   (i<32)
// out[i+32] = x[2i]*sin + x[2i+1]*cos
// ---------------------------------------------------------------------------
__global__ __launch_bounds__(256) void rope_kernel(short* __restrict__ Q, short* __restrict__ K) {
    const int rid = blockIdx.x * 256 + threadIdx.x;   // 0..131071
    short* buf = (rid & 65536) ? K : Q;
    const int r2 = rid & 65535;          // bh*2048 + t
    const int t = r2 & 2047;
    short* row = buf + (size_t)r2 * 64;

    unsigned wv[32];
    const uint4* rp = (const uint4*)row;
#pragma unroll
    for (int c = 0; c < 8; c++) {
        uint4 v = rp[c];
        wv[c * 4 + 0] = v.x; wv[c * 4 + 1] = v.y; wv[c * 4 + 2] = v.z; wv[c * 4 + 3] = v.w;
    }
    float y1[32], y2[32];
    const float tf = (float)t;
#pragma unroll
    for (int i = 0; i < 32; i++) {
        float x1 = bf2f((short)(wv[i] & 0xFFFFu));
        float x2 = bf2f((short)(wv[i] >> 16));
        float inv = expf(-9.2103403719761836f * (float)i * (1.0f / 32.0f));  // 10000^(-i/32)
        float fr = tf * inv;
        float sn, cs;
        sincosf(fr, &sn, &cs);
        y1[i] = x1 * cs - x2 * sn;
        y2[i] = x1 * sn + x2 * cs;
    }
    unsigned ow[32];
#pragma unroll
    for (int i = 0; i < 16; i++) ow[i] = pack2(y1[2 * i], y1[2 * i + 1]);
#pragma unroll
    for (int i = 0; i < 16; i++) ow[16 + i] = pack2(y2[2 * i], y2[2 * i + 1]);
    uint4* wp = (uint4*)row;
#pragma unroll
    for (int c = 0; c < 8; c++)
        wp[c] = make_uint4(ow[c * 4 + 0], ow[c * 4 + 1], ow[c * 4 + 2], ow[c * 4 + 3]);
}

// ---------------------------------------------------------------------------
// Kernel 3: causal flash attention. Block = (qt, bh); 64 q-rows, 4 waves
// (16 rows each). K-tiles of 64 keys; online softmax; P goes C-layout ->
// LDS -> A-layout for the PV MFMA; V transposed into LDS at staging.
// Output written to Y in [B,T,H*D] bf16.
// ---------------------------------------------------------------------------
__global__ __launch_bounds__(256) void attn_kernel(
    const short* __restrict__ Q, const short* __restrict__ K,
    const short* __restrict__ V, short* __restrict__ Y) {
    __shared__ short sQl[64 * LDP];
    __shared__ short sK[64 * LDP];
    __shared__ short sVT[64 * LDP];
    __shared__ short sP[64 * LDP];

    const int tid = threadIdx.x;
    const int w = tid >> 6, lane = tid & 63, quad = lane >> 4, l15 = lane & 15;
    const int qt = blockIdx.x;           // 0..31
    const int bh = blockIdx.y;           // 0..31
    const int b = bh >> 4, h = bh & 15;
    const short* Qp = Q + (size_t)bh * 2048 * 64;
    const short* Kp = K + (size_t)bh * 2048 * 64;
    const short* Vp = V + (size_t)bh * 2048 * 64;

    // stage Q tile (64 rows x 64 dims)
#pragma unroll
    for (int i = 0; i < 2; i++) {
        int p = tid + i * 256;           // 512 uint4 slots: 64 rows x 8
        int row = p >> 3, c8 = p & 7;
        uint4 v = *(const uint4*)(Qp + (size_t)(qt * 64 + row) * 64 + c8 * 8);
        *(uint4*)&sQl[row * LDP + c8 * 8] = v;
    }
    __syncthreads();
    s16x8 aq[2];
#pragma unroll
    for (int ks = 0; ks < 2; ks++)
        aq[ks] = *(const s16x8*)&sQl[(w * 16 + l15) * LDP + ks * 32 + quad * 8];

    f32x4 o[4];
#pragma unroll
    for (int i = 0; i < 4; i++) o[i] = f32x4{0.f, 0.f, 0.f, 0.f};
    float mrun[4] = {-INFINITY, -INFINITY, -INFINITY, -INFINITY};
    float lrun[4] = {0.f, 0.f, 0.f, 0.f};

    for (int kt = 0; kt <= qt; kt++) {
        __syncthreads();                 // protect sK/sVT from prior-iter readers
        // stage K (row-major) and V (transposed) tiles
#pragma unroll
        for (int i = 0; i < 2; i++) {
            int p = tid + i * 256;
            int row = p >> 3, c8 = p & 7;
            uint4 kv = *(const uint4*)(Kp + (size_t)(kt * 64 + row) * 64 + c8 * 8);
            *(uint4*)&sK[row * LDP + c8 * 8] = kv;
            uint4 vv = *(const uint4*)(Vp + (size_t)(kt * 64 + row) * 64 + c8 * 8);
            unsigned vs[4] = {vv.x, vv.y, vv.z, vv.w};
#pragma unroll
            for (int j = 0; j < 4; j++) {
                sVT[(c8 * 8 + 2 * j + 0) * LDP + row] = (short)(vs[j] & 0xFFFFu);
                sVT[(c8 * 8 + 2 * j + 1) * LDP + row] = (short)(vs[j] >> 16);
            }
        }
        __syncthreads();

        // S = Q K^T  (per wave: 16 q-rows x 64 keys)
        f32x4 sa[4];
#pragma unroll
        for (int i = 0; i < 4; i++) sa[i] = f32x4{0.f, 0.f, 0.f, 0.f};
#pragma unroll
        for (int ks = 0; ks < 2; ks++) {
            s16x8 a = aq[ks];
#pragma unroll
            for (int ct = 0; ct < 4; ct++) {
                s16x8 bfr = *(const s16x8*)&sK[(ct * 16 + l15) * LDP + ks * 32 + quad * 8];
                sa[ct] = MFMA16(a, bfr, sa[ct]);
            }
        }

        const bool diag = (kt == qt);
        float pv[4][4];
#pragma unroll
        for (int r = 0; r < 4; r++) {
            const int q_idx = qt * 64 + w * 16 + quad * 4 + r;
            float mx = -INFINITY;
#pragma unroll
            for (int ct = 0; ct < 4; ct++) {
                float s = sa[ct][r] * 0.125f;
                if (diag && (kt * 64 + ct * 16 + l15) > q_idx) s = -INFINITY;
                pv[ct][r] = s;
                mx = fmaxf(mx, s);
            }
            mx = qmax16(mx);
            float mnew = fmaxf(mrun[r], mx);
            float alpha = __expf(mrun[r] - mnew);
            float psum = 0.f;
#pragma unroll
            for (int ct = 0; ct < 4; ct++) {
                float p = __expf(pv[ct][r] - mnew);
                pv[ct][r] = p;
                psum += p;
            }
            psum = qsum16(psum);
            lrun[r] = lrun[r] * alpha + psum;
            mrun[r] = mnew;
#pragma unroll
            for (int ct = 0; ct < 4; ct++) o[ct][r] *= alpha;
        }

        // P: C-layout regs -> LDS (wave-private region)
#pragma unroll
        for (int ct = 0; ct < 4; ct++)
#pragma unroll
            for (int r = 0; r < 4; r++)
                sP[(w * 16 + quad * 4 + r) * LDP + ct * 16 + l15] = f2bf(pv[ct][r]);
        __syncthreads();                 // cross-lane LDS ordering (safe for round 0)

        // O += P V
#pragma unroll
        for (int ks2 = 0; ks2 < 2; ks2++) {
            s16x8 pa = *(const s16x8*)&sP[(w * 16 + l15) * LDP + ks2 * 32 + quad * 8];
#pragma unroll
            for (int ct = 0; ct < 4; ct++) {
                s16x8 vb = *(const s16x8*)&sVT[(ct * 16 + l15) * LDP + ks2 * 32 + quad * 8];
                o[ct] = MFMA16(pa, vb, o[ct]);
            }
        }
    }

    // epilogue: normalize and store Y[b, t, h*64+d] (bf16)
#pragma unroll
    for (int r = 0; r < 4; r++) {
        float inv = 1.0f / lrun[r];
        int t = qt * 64 + w * 16 + quad * 4 + r;
#pragma unroll
        for (int ct = 0; ct < 4; ct++) {
            float val = o[ct][r] * inv;
            Y[((size_t)(b * 2048 + t)) * 1024 + h * 64 + ct * 16 + l15] = f2bf(val);
        }
    }
}

// ---------------------------------------------------------------------------
// Kernel 4: output projection. out[m,n] = sum_k Y[m,k] * Wo[n,k], fp32 out.
// ---------------------------------------------------------------------------
__global__ __launch_bounds__(256) void oproj_kernel(
    const short* __restrict__ Yb, const float* __restrict__ Wo, float* __restrict__ out) {
    __shared__ short sA[64 * LDP];
    __shared__ short sB[64 * LDP];
    const int tid = threadIdx.x;
    const int w = tid >> 6, lane = tid & 63, quad = lane >> 4, l15 = lane & 15;
    const int n0 = blockIdx.x * 64;
    const int m0 = blockIdx.y * 64;

    f32x4 acc[4];
#pragma unroll
    for (int i = 0; i < 4; i++) acc[i] = f32x4{0.f, 0.f, 0.f, 0.f};

    for (int kb = 0; kb < 16; kb++) {
        const int k0 = kb * 64;
        if (kb) __syncthreads();
#pragma unroll
        for (int i = 0; i < 2; i++) {     // A: bf16 source, 512 uint4 slots
            int p = tid + i * 256;
            int row = p >> 3, c8 = p & 7;
            uint4 v = *(const uint4*)(Yb + (size_t)(m0 + row) * 1024 + k0 + c8 * 8);
            *(uint4*)&sA[row * LDP + c8 * 8] = v;
        }
#pragma unroll
        for (int i = 0; i < 4; i++) {     // B: fp32 source, convert
            int p = tid + i * 256;
            int row = p >> 4, c4 = p & 15;
            float4 bv = *(const float4*)(Wo + (size_t)(n0 + row) * 1024 + k0 + c4 * 4);
            *(uint2*)&sB[row * LDP + c4 * 4] = make_uint2(pack2(bv.x, bv.y), pack2(bv.z, bv.w));
        }
        __syncthreads();
#pragma unroll
        for (int ks = 0; ks < 2; ks++) {
            s16x8 a = *(const s16x8*)&sA[(w * 16 + l15) * LDP + ks * 32 + quad * 8];
#pragma unroll
            for (int ct = 0; ct < 4; ct++) {
                s16x8 b = *(const s16x8*)&sB[(ct * 16 + l15) * LDP + ks * 32 + quad * 8];
                acc[ct] = MFMA16(a, b, acc[ct]);
            }
        }
    }
#pragma unroll
    for (int ct = 0; ct < 4; ct++)
#pragma unroll
        for (int r = 0; r < 4; r++) {
            int m = m0 + w * 16 + quad * 4 + r;
            out[(size_t)m * 1024 + n0 + ct * 16 + l15] = acc[ct][r];
        }
}

extern "C" void kernel_launch(void* const* d_in, const int* in_sizes, int n_in,
                              void* d_out, int out_size, void* d_ws, size_t ws_size,
                              hipStream_t stream) {
    (void)in_sizes; (void)n_in; (void)out_size; (void)ws_size;
    const float* x  = (const float*)d_in[0];
    const float* Wq = (const float*)d_in[1];
    const float* Wk = (const float*)d_in[2];
    const float* Wv = (const float*)d_in[3];
    const float* Wo = (const float*)d_in[4];
    float* out = (float*)d_out;

    const size_t NE = (size_t)2 * 16 * 2048 * 64;   // 4M elems per tensor
    short* Q = (short*)d_ws;
    short* K = Q + NE;
    short* V = K + NE;
    short* Y = V + NE;                               // total 32 MB bf16 scratch

    qkv_kernel<<<dim3(48, 64), 256, 0, stream>>>(x, Wq, Wk, Wv, Q, K, V);
    rope_kernel<<<512, 256, 0, stream>>>(Q, K);
    attn_kernel<<<dim3(32, 32), 256, 0, stream>>>(Q, K, V, Y);
    oproj_kernel<<<dim3(16, 64), 256, 0, stream>>>(Y, Wo, out);
}

// Round 2
// 304.183 us; speedup vs baseline: 1.3966x; 1.3966x over previous
//
#include <hip/hip_runtime.h>
#include <cstdint>
#include <cstddef>

typedef short s16x8 __attribute__((ext_vector_type(8)));
typedef float f32x4 __attribute__((ext_vector_type(4)));

#define MFMA16(a, b, c) __builtin_amdgcn_mfma_f32_16x16x32_bf16((a), (b), (c), 0, 0, 0)

constexpr int LDP = 72;  // padded LDS row stride (bf16 elems); 144 B keeps b128 16B-aligned, 2-way bank alias (free)

__device__ __forceinline__ short f2bf(float f) {
    unsigned u = __builtin_bit_cast(unsigned, f);
    u += 0x7FFFu + ((u >> 16) & 1u);   // RNE
    return (short)(u >> 16);
}
__device__ __forceinline__ float bf2f(short s) {
    unsigned u = ((unsigned)(unsigned short)s) << 16;
    return __builtin_bit_cast(float, u);
}
__device__ __forceinline__ unsigned pack2(float a, float b) {
    return (unsigned)(unsigned short)f2bf(a) | ((unsigned)(unsigned short)f2bf(b) << 16);
}
__device__ __forceinline__ float qmax16(float v) {
    v = fmaxf(v, __shfl_xor(v, 1));
    v = fmaxf(v, __shfl_xor(v, 2));
    v = fmaxf(v, __shfl_xor(v, 4));
    v = fmaxf(v, __shfl_xor(v, 8));
    return v;
}
__device__ __forceinline__ float qsum16(float v) {
    v += __shfl_xor(v, 1);
    v += __shfl_xor(v, 2);
    v += __shfl_xor(v, 4);
    v += __shfl_xor(v, 8);
    return v;
}

// ---------------------------------------------------------------------------
// Kernel 1: QKV projection. C[m,n] = sum_k x[m,k] * W[n,k]  (NT GEMM)
// M=4096 (B*T), N=3072 (q|k|v), K=1024. Tile 64x64, BK=64, 4 waves.
// Q,K written [B,H,T,D] bf16; V written TRANSPOSED [B,H,D,T] bf16 so the
// attention kernel never has to transpose it (was an 8-way-bank-conflict
// scalar-store transpose, redone per (qt,kt) pair).
// ---------------------------------------------------------------------------
__global__ __launch_bounds__(256) void qkv_kernel(
    const float* __restrict__ x, const float* __restrict__ Wq,
    const float* __restrict__ Wk, const float* __restrict__ Wv,
    short* __restrict__ Qo, short* __restrict__ Ko, short* __restrict__ VTo) {
    __shared__ short sA[64 * LDP];
    __shared__ short sB[64 * LDP];
    const int tid = threadIdx.x;
    const int w = tid >> 6, lane = tid & 63, quad = lane >> 4, l15 = lane & 15;
    const int bx = blockIdx.x, by = blockIdx.y;
    const int wsel = bx >> 4;           // 0=q 1=k 2=v
    const int h = bx & 15;              // head (64 cols == one head)
    const float* W = (wsel == 0) ? Wq : ((wsel == 1) ? Wk : Wv);
    const int n0 = h * 64;
    const int m0 = by * 64;

    f32x4 acc[4];
#pragma unroll
    for (int i = 0; i < 4; i++) acc[i] = f32x4{0.f, 0.f, 0.f, 0.f};

    for (int kb = 0; kb < 16; kb++) {
        const int k0 = kb * 64;
        if (kb) __syncthreads();
#pragma unroll
        for (int i = 0; i < 4; i++) {
            int p = tid + i * 256;          // 1024 float4 slots: 64 rows x 16
            int row = p >> 4, c4 = p & 15;
            float4 av = *(const float4*)(x + (size_t)(m0 + row) * 1024 + k0 + c4 * 4);
            float4 bv = *(const float4*)(W + (size_t)(n0 + row) * 1024 + k0 + c4 * 4);
            *(uint2*)&sA[row * LDP + c4 * 4] = make_uint2(pack2(av.x, av.y), pack2(av.z, av.w));
            *(uint2*)&sB[row * LDP + c4 * 4] = make_uint2(pack2(bv.x, bv.y), pack2(bv.z, bv.w));
        }
        __syncthreads();
#pragma unroll
        for (int ks = 0; ks < 2; ks++) {
            s16x8 a = *(const s16x8*)&sA[(w * 16 + l15) * LDP + ks * 32 + quad * 8];
#pragma unroll
            for (int ct = 0; ct < 4; ct++) {
                s16x8 b = *(const s16x8*)&sB[(ct * 16 + l15) * LDP + ks * 32 + quad * 8];
                acc[ct] = MFMA16(a, b, acc[ct]);
            }
        }
    }

    const int b = m0 >> 11;             // tile never crosses batch boundary (64 | 2048)
    if (wsel == 2) {
        // V^T epilogue: VT[(b*16+h)*64 + d][t], lane packs 4 consecutive t
        const int t0 = (m0 & 2047) + w * 16 + quad * 4;
        const size_t base = ((size_t)((b * 16 + h) * 64)) * 2048;
#pragma unroll
        for (int ct = 0; ct < 4; ct++) {
            int d = ct * 16 + l15;
            unsigned lo = pack2(acc[ct][0], acc[ct][1]);
            unsigned hi = pack2(acc[ct][2], acc[ct][3]);
            *(uint2*)&VTo[base + (size_t)d * 2048 + t0] = make_uint2(lo, hi);
        }
    } else {
        short* Out = (wsel == 0) ? Qo : Ko;
#pragma unroll
        for (int ct = 0; ct < 4; ct++)
#pragma unroll
            for (int r = 0; r < 4; r++) {
                int t = (m0 & 2047) + w * 16 + quad * 4 + r;
                size_t idx = (((size_t)(b * 16 + h)) * 2048 + t) * 64 + ct * 16 + l15;
                Out[idx] = f2bf(acc[ct][r]);
            }
    }
}

// ---------------------------------------------------------------------------
// Kernel 2: RoPE in-place on Q and K ([B,H,T,D] bf16). One thread per row.
// Q additionally pre-scaled by 1/8 (softmax 1/sqrt(D)) so attention skips it.
// ---------------------------------------------------------------------------
__global__ __launch_bounds__(256) void rope_kernel(short* __restrict__ Q, short* __restrict__ K) {
    const int rid = blockIdx.x * 256 + threadIdx.x;   // 0..131071
    const bool isK = (rid & 65536) != 0;
    short* buf = isK ? K : Q;
    const float sc = isK ? 1.0f : 0.125f;
    const int r2 = rid & 65535;          // bh*2048 + t
    const int t = r2 & 2047;
    short* row = buf + (size_t)r2 * 64;

    unsigned wv[32];
    const uint4* rp = (const uint4*)row;
#pragma unroll
    for (int c = 0; c < 8; c++) {
        uint4 v = rp[c];
        wv[c * 4 + 0] = v.x; wv[c * 4 + 1] = v.y; wv[c * 4 + 2] = v.z; wv[c * 4 + 3] = v.w;
    }
    float y1[32], y2[32];
    const float tf = (float)t;
#pragma unroll
    for (int i = 0; i < 32; i++) {
        float x1 = bf2f((short)(wv[i] & 0xFFFFu));
        float x2 = bf2f((short)(wv[i] >> 16));
        float inv = expf(-9.2103403719761836f * (float)i * (1.0f / 32.0f));  // 10000^(-i/32)
        float fr = tf * inv;
        float sn, cs;
        sincosf(fr, &sn, &cs);
        y1[i] = (x1 * cs - x2 * sn) * sc;
        y2[i] = (x1 * sn + x2 * cs) * sc;
    }
    unsigned ow[32];
#pragma unroll
    for (int i = 0; i < 16; i++) ow[i] = pack2(y1[2 * i], y1[2 * i + 1]);
#pragma unroll
    for (int i = 0; i < 16; i++) ow[16 + i] = pack2(y2[2 * i], y2[2 * i + 1]);
    uint4* wp = (uint4*)row;
#pragma unroll
    for (int c = 0; c < 8; c++)
        wp[c] = make_uint4(ow[c * 4 + 0], ow[c * 4 + 1], ow[c * 4 + 2], ow[c * 4 + 3]);
}

// ---------------------------------------------------------------------------
// Kernel 3: causal flash attention, LOAD-BALANCED. Each block handles the
// q-tile pair (px, 31-px): (px+1) + (32-px) = 33 K-tile iterations for every
// block, so all 512 blocks finish together (fixes the qt==CU%32 aliasing that
// starved the machine). V comes in pre-transposed [B,H,D,T]. sP aliases the
// dead sQ buffer (Q lives in registers after the prologue) -> 27.6 KB LDS.
// sP rows are wave-private; DS ops from one wave are in-order, so no barrier
// between the sP write and the PV fragment read.
// ---------------------------------------------------------------------------
__global__ __launch_bounds__(256) void attn_kernel(
    const short* __restrict__ Q, const short* __restrict__ K,
    const short* __restrict__ VT, short* __restrict__ Y) {
    __shared__ short sQP[64 * LDP];   // Q tile during prologue, then P
    __shared__ short sK[64 * LDP];
    __shared__ short sVT[64 * LDP];

    const int tid = threadIdx.x;
    const int w = tid >> 6, lane = tid & 63, quad = lane >> 4, l15 = lane & 15;
    const int px = blockIdx.x;           // 0..15
    const int bh = blockIdx.y;           // 0..31
    const int b = bh >> 4, h = bh & 15;
    const short* Qp = Q + (size_t)bh * 2048 * 64;
    const short* Kp = K + (size_t)bh * 2048 * 64;
    const short* Vp = VT + (size_t)bh * 64 * 2048;   // [d][t]

    for (int pass = 0; pass < 2; pass++) {
        const int qt = pass ? (31 - px) : px;
        __syncthreads();                 // prior pass's sP readers done before Q reload
        // stage Q tile (64 rows x 64 dims)
#pragma unroll
        for (int i = 0; i < 2; i++) {
            int p = tid + i * 256;       // 512 uint4 slots: 64 rows x 8
            int row = p >> 3, c8 = p & 7;
            uint4 v = *(const uint4*)(Qp + (size_t)(qt * 64 + row) * 64 + c8 * 8);
            *(uint4*)&sQP[row * LDP + c8 * 8] = v;
        }
        __syncthreads();
        s16x8 aq[2];
#pragma unroll
        for (int ks = 0; ks < 2; ks++)
            aq[ks] = *(const s16x8*)&sQP[(w * 16 + l15) * LDP + ks * 32 + quad * 8];

        f32x4 o[4];
#pragma unroll
        for (int i = 0; i < 4; i++) o[i] = f32x4{0.f, 0.f, 0.f, 0.f};
        float mrun[4] = {-INFINITY, -INFINITY, -INFINITY, -INFINITY};
        float lrun[4] = {0.f, 0.f, 0.f, 0.f};

        for (int kt = 0; kt <= qt; kt++) {
            __syncthreads();             // prior iter's sK/sVT readers done (also covers aq reads)
#pragma unroll
            for (int i = 0; i < 2; i++) {
                int p = tid + i * 256;
                int row = p >> 3, c8 = p & 7;
                uint4 kv = *(const uint4*)(Kp + (size_t)(kt * 64 + row) * 64 + c8 * 8);
                *(uint4*)&sK[row * LDP + c8 * 8] = kv;
                uint4 vv = *(const uint4*)(Vp + (size_t)row * 2048 + kt * 64 + c8 * 8);
                *(uint4*)&sVT[row * LDP + c8 * 8] = vv;   // row = d, cols = keys
            }
            __syncthreads();

            // S = Q K^T  (per wave: 16 q-rows x 64 keys); 1/8 scale folded into Q
            f32x4 sa[4];
#pragma unroll
            for (int i = 0; i < 4; i++) sa[i] = f32x4{0.f, 0.f, 0.f, 0.f};
#pragma unroll
            for (int ks = 0; ks < 2; ks++) {
                s16x8 a = aq[ks];
#pragma unroll
                for (int ct = 0; ct < 4; ct++) {
                    s16x8 bfr = *(const s16x8*)&sK[(ct * 16 + l15) * LDP + ks * 32 + quad * 8];
                    sa[ct] = MFMA16(a, bfr, sa[ct]);
                }
            }

            const bool diag = (kt == qt);
            float pv[4][4];
#pragma unroll
            for (int r = 0; r < 4; r++) {
                const int q_idx = qt * 64 + w * 16 + quad * 4 + r;
                float mx = -INFINITY;
#pragma unroll
                for (int ct = 0; ct < 4; ct++) {
                    float s = sa[ct][r];
                    if (diag && (kt * 64 + ct * 16 + l15) > q_idx) s = -INFINITY;
                    pv[ct][r] = s;
                    mx = fmaxf(mx, s);
                }
                mx = qmax16(mx);
                float mnew = fmaxf(mrun[r], mx);
                float alpha = __expf(mrun[r] - mnew);
                float psum = 0.f;
#pragma unroll
                for (int ct = 0; ct < 4; ct++) {
                    float p = __expf(pv[ct][r] - mnew);
                    pv[ct][r] = p;
                    psum += p;
                }
                psum = qsum16(psum);
                lrun[r] = lrun[r] * alpha + psum;
                mrun[r] = mnew;
#pragma unroll
                for (int ct = 0; ct < 4; ct++) o[ct][r] *= alpha;
            }

            // P: C-layout regs -> LDS (wave-private 16-row slab of sQP)
#pragma unroll
            for (int ct = 0; ct < 4; ct++)
#pragma unroll
                for (int r = 0; r < 4; r++)
                    sQP[(w * 16 + quad * 4 + r) * LDP + ct * 16 + l15] = f2bf(pv[ct][r]);
            // no barrier: same-wave DS ops are in-order, rows are wave-private

            // O += P V
#pragma unroll
            for (int ks2 = 0; ks2 < 2; ks2++) {
                s16x8 pa = *(const s16x8*)&sQP[(w * 16 + l15) * LDP + ks2 * 32 + quad * 8];
#pragma unroll
                for (int ct = 0; ct < 4; ct++) {
                    s16x8 vb = *(const s16x8*)&sVT[(ct * 16 + l15) * LDP + ks2 * 32 + quad * 8];
                    o[ct] = MFMA16(pa, vb, o[ct]);
                }
            }
        }

        // epilogue: normalize and store Y[b, t, h*64+d] (bf16)
#pragma unroll
        for (int r = 0; r < 4; r++) {
            float inv = 1.0f / lrun[r];
            int t = qt * 64 + w * 16 + quad * 4 + r;
#pragma unroll
            for (int ct = 0; ct < 4; ct++) {
                float val = o[ct][r] * inv;
                Y[((size_t)(b * 2048 + t)) * 1024 + h * 64 + ct * 16 + l15] = f2bf(val);
            }
        }
    }
}

// ---------------------------------------------------------------------------
// Kernel 4: output projection. out[m,n] = sum_k Y[m,k] * Wo[n,k], fp32 out.
// ---------------------------------------------------------------------------
__global__ __launch_bounds__(256) void oproj_kernel(
    const short* __restrict__ Yb, const float* __restrict__ Wo, float* __restrict__ out) {
    __shared__ short sA[64 * LDP];
    __shared__ short sB[64 * LDP];
    const int tid = threadIdx.x;
    const int w = tid >> 6, lane = tid & 63, quad = lane >> 4, l15 = lane & 15;
    const int n0 = blockIdx.x * 64;
    const int m0 = blockIdx.y * 64;

    f32x4 acc[4];
#pragma unroll
    for (int i = 0; i < 4; i++) acc[i] = f32x4{0.f, 0.f, 0.f, 0.f};

    for (int kb = 0; kb < 16; kb++) {
        const int k0 = kb * 64;
        if (kb) __syncthreads();
#pragma unroll
        for (int i = 0; i < 2; i++) {     // A: bf16 source, 512 uint4 slots
            int p = tid + i * 256;
            int row = p >> 3, c8 = p & 7;
            uint4 v = *(const uint4*)(Yb + (size_t)(m0 + row) * 1024 + k0 + c8 * 8);
            *(uint4*)&sA[row * LDP + c8 * 8] = v;
        }
#pragma unroll
        for (int i = 0; i < 4; i++) {     // B: fp32 source, convert
            int p = tid + i * 256;
            int row = p >> 4, c4 = p & 15;
            float4 bv = *(const float4*)(Wo + (size_t)(n0 + row) * 1024 + k0 + c4 * 4);
            *(uint2*)&sB[row * LDP + c4 * 4] = make_uint2(pack2(bv.x, bv.y), pack2(bv.z, bv.w));
        }
        __syncthreads();
#pragma unroll
        for (int ks = 0; ks < 2; ks++) {
            s16x8 a = *(const s16x8*)&sA[(w * 16 + l15) * LDP + ks * 32 + quad * 8];
#pragma unroll
            for (int ct = 0; ct < 4; ct++) {
                s16x8 b = *(const s16x8*)&sB[(ct * 16 + l15) * LDP + ks * 32 + quad * 8];
                acc[ct] = MFMA16(a, b, acc[ct]);
            }
        }
    }
#pragma unroll
    for (int ct = 0; ct < 4; ct++)
#pragma unroll
        for (int r = 0; r < 4; r++) {
            int m = m0 + w * 16 + quad * 4 + r;
            out[(size_t)m * 1024 + n0 + ct * 16 + l15] = acc[ct][r];
        }
}

extern "C" void kernel_launch(void* const* d_in, const int* in_sizes, int n_in,
                              void* d_out, int out_size, void* d_ws, size_t ws_size,
                              hipStream_t stream) {
    (void)in_sizes; (void)n_in; (void)out_size; (void)ws_size;
    const float* x  = (const float*)d_in[0];
    const float* Wq = (const float*)d_in[1];
    const float* Wk = (const float*)d_in[2];
    const float* Wv = (const float*)d_in[3];
    const float* Wo = (const float*)d_in[4];
    float* out = (float*)d_out;

    const size_t NE = (size_t)2 * 16 * 2048 * 64;   // 4M elems per tensor
    short* Q  = (short*)d_ws;
    short* K  = Q + NE;
    short* VT = K + NE;                              // [B,H,D,T]
    short* Y  = VT + NE;                             // total 32 MB bf16 scratch

    qkv_kernel<<<dim3(48, 64), 256, 0, stream>>>(x, Wq, Wk, Wv, Q, K, VT);
    rope_kernel<<<512, 256, 0, stream>>>(Q, K);
    attn_kernel<<<dim3(16, 32), 256, 0, stream>>>(Q, K, VT, Y);
    oproj_kernel<<<dim3(16, 64), 256, 0, stream>>>(Y, Wo, out);
}

// Round 3
// 237.258 us; speedup vs baseline: 1.7906x; 1.2821x over previous
//
#include <hip/hip_runtime.h>
#include <cstdint>
#include <cstddef>

typedef short s16x8 __attribute__((ext_vector_type(8)));
typedef float f32x4 __attribute__((ext_vector_type(4)));

#define MFMA16(a, b, c) __builtin_amdgcn_mfma_f32_16x16x32_bf16((a), (b), (c), 0, 0, 0)

constexpr int LDP = 72;  // padded LDS row stride for attn tiles (2-way bank alias = free)

__device__ __forceinline__ short f2bf(float f) {
    unsigned u = __builtin_bit_cast(unsigned, f);
    u += 0x7FFFu + ((u >> 16) & 1u);   // RNE
    return (short)(u >> 16);
}
__device__ __forceinline__ float bf2f(short s) {
    unsigned u = ((unsigned)(unsigned short)s) << 16;
    return __builtin_bit_cast(float, u);
}
__device__ __forceinline__ unsigned pack2(float a, float b) {
    return (unsigned)(unsigned short)f2bf(a) | ((unsigned)(unsigned short)f2bf(b) << 16);
}

// async 16B/lane global->LDS copy (global_load_lds_dwordx4). LDS dest must be
// wave-uniform base; HW adds lane*16.
__device__ __forceinline__ void async_ld16(const void* g, void* l) {
    __builtin_amdgcn_global_load_lds(
        (const __attribute__((address_space(1))) unsigned int*)g,
        (__attribute__((address_space(3))) unsigned int*)l, 16, 0, 0);
}

// ---------------------------------------------------------------------------
// Kernel 0: fp32 -> bf16 convert of x and all four weights (once per call).
// xb gets x (4M elems); wb gets [Wq|Wk|Wv|Wo] stacked (4M elems).
// ---------------------------------------------------------------------------
__global__ __launch_bounds__(256) void convert_kernel(
    const float* __restrict__ x, const float* __restrict__ Wq,
    const float* __restrict__ Wk, const float* __restrict__ Wv,
    const float* __restrict__ Wo, short* __restrict__ xb, short* __restrict__ wb) {
    const size_t f = ((size_t)blockIdx.x * 256 + threadIdx.x) * 8;   // 8 floats/thread
    const float* src;
    short* dst;
    if (f < 4194304) { src = x + f; dst = xb + f; }
    else {
        size_t wo = f - 4194304;
        int seg = (int)(wo >> 20);
        const float* ws4[4] = {Wq, Wk, Wv, Wo};
        src = ws4[seg] + (wo & 1048575u);
        dst = wb + wo;
    }
    float4 a = ((const float4*)src)[0];
    float4 b = ((const float4*)src)[1];
    *(uint4*)dst = make_uint4(pack2(a.x, a.y), pack2(a.z, a.w),
                              pack2(b.x, b.y), pack2(b.z, b.w));
}

// ---------------------------------------------------------------------------
// Kernel 1: QKV projection, m97-structure. C[m,n] = sum_k xb[m,k]*W[n,k].
// M=4096, N=3072 ([Wq|Wk|Wv] rows), K=1024. 128x128 tile, BK=64, 4 waves
// (2x2), global_load_lds width-16 staging, unpadded LDS tiles.
// Q,K scatter to [B,H,T,D] bf16; V to [B,H,D,T] bf16 (pre-transposed).
// ---------------------------------------------------------------------------
__global__ __launch_bounds__(256) void qkv_kernel(
    const short* __restrict__ xb, const short* __restrict__ wb,
    short* __restrict__ Qo, short* __restrict__ Ko, short* __restrict__ VTo) {
    __shared__ __align__(16) short sA[128 * 64];
    __shared__ __align__(16) short sB[128 * 64];
    const int tid = threadIdx.x;
    const int w = tid >> 6, lane = tid & 63, quad = lane >> 4, l15 = lane & 15;
    const int wm = w & 1, wn = w >> 1;
    const int bx = blockIdx.x, by = blockIdx.y;
    const int m0 = by * 128;
    const int nb = bx * 128;

    f32x4 acc[4][4];
#pragma unroll
    for (int i = 0; i < 4; i++)
#pragma unroll
        for (int j = 0; j < 4; j++) acc[i][j] = f32x4{0.f, 0.f, 0.f, 0.f};

    for (int kb = 0; kb < 16; kb++) {
        const int k0 = kb * 64;
        if (kb) __syncthreads();
#pragma unroll
        for (int i = 0; i < 4; i++) {
            int c = i * 256 + tid;             // 16B chunk id, 1024 per 16KB tile
            int row = c >> 3, col8 = (c & 7) * 8;
            async_ld16(xb + (size_t)(m0 + row) * 1024 + k0 + col8,
                       &sA[(i * 256 + w * 64) * 8]);
            async_ld16(wb + (size_t)(nb + row) * 1024 + k0 + col8,
                       &sB[(i * 256 + w * 64) * 8]);
        }
        __syncthreads();
#pragma unroll
        for (int ks = 0; ks < 2; ks++) {
            s16x8 av[4], bv[4];
#pragma unroll
            for (int at = 0; at < 4; at++)
                av[at] = *(const s16x8*)&sA[(wm * 64 + at * 16 + l15) * 64 + ks * 32 + quad * 8];
#pragma unroll
            for (int bt = 0; bt < 4; bt++)
                bv[bt] = *(const s16x8*)&sB[(wn * 64 + bt * 16 + l15) * 64 + ks * 32 + quad * 8];
#pragma unroll
            for (int at = 0; at < 4; at++)
#pragma unroll
                for (int bt = 0; bt < 4; bt++)
                    acc[at][bt] = MFMA16(av[at], bv[bt], acc[at][bt]);
        }
    }

    const int wsel = bx >> 3;                 // 0=q 1=k 2=v
    const int h = (bx & 7) * 2 + wn;          // head (uniform per wave)
    if (wsel == 2) {
#pragma unroll
        for (int at = 0; at < 4; at++) {
            int m = m0 + wm * 64 + at * 16 + quad * 4;
            int b = m >> 11, t0 = m & 2047;
            size_t base = ((size_t)((b * 16 + h) * 64)) * 2048;
#pragma unroll
            for (int bt = 0; bt < 4; bt++) {
                int d = bt * 16 + l15;
                unsigned lo = pack2(acc[at][bt][0], acc[at][bt][1]);
                unsigned hi = pack2(acc[at][bt][2], acc[at][bt][3]);
                *(uint2*)&VTo[base + (size_t)d * 2048 + t0] = make_uint2(lo, hi);
            }
        }
    } else {
        short* Out = (wsel == 0) ? Qo : Ko;
#pragma unroll
        for (int at = 0; at < 4; at++)
#pragma unroll
            for (int r = 0; r < 4; r++) {
                int m = m0 + wm * 64 + at * 16 + quad * 4 + r;
                int b = m >> 11, t = m & 2047;
                size_t base = (((size_t)(b * 16 + h)) * 2048 + t) * 64;
#pragma unroll
                for (int bt = 0; bt < 4; bt++)
                    Out[base + bt * 16 + l15] = f2bf(acc[at][bt][r]);
            }
    }
}

// ---------------------------------------------------------------------------
// Kernel 2: RoPE in-place on Q and K ([B,H,T,D] bf16). One thread per row.
// Q pre-scaled by 0.125*log2(e) so attention works in exp2 domain.
// ---------------------------------------------------------------------------
__global__ __launch_bounds__(256) void rope_kernel(short* __restrict__ Q, short* __restrict__ K) {
    const int rid = blockIdx.x * 256 + threadIdx.x;   // 0..131071
    const bool isK = (rid & 65536) != 0;
    short* buf = isK ? K : Q;
    const float sc = isK ? 1.0f : 0.18033688011112042f;   // 1/8 * log2(e)
    const int r2 = rid & 65535;          // bh*2048 + t
    const int t = r2 & 2047;
    short* row = buf + (size_t)r2 * 64;

    unsigned wv[32];
    const uint4* rp = (const uint4*)row;
#pragma unroll
    for (int c = 0; c < 8; c++) {
        uint4 v = rp[c];
        wv[c * 4 + 0] = v.x; wv[c * 4 + 1] = v.y; wv[c * 4 + 2] = v.z; wv[c * 4 + 3] = v.w;
    }
    float y1[32], y2[32];
    const float tf = (float)t;
#pragma unroll
    for (int i = 0; i < 32; i++) {
        float x1 = bf2f((short)(wv[i] & 0xFFFFu));
        float x2 = bf2f((short)(wv[i] >> 16));
        float inv = expf(-9.2103403719761836f * (float)i * (1.0f / 32.0f));  // 10000^(-i/32)
        float fr = tf * inv;
        float sn, cs;
        sincosf(fr, &sn, &cs);
        y1[i] = (x1 * cs - x2 * sn) * sc;
        y2[i] = (x1 * sn + x2 * cs) * sc;
    }
    unsigned ow[32];
#pragma unroll
    for (int i = 0; i < 16; i++) ow[i] = pack2(y1[2 * i], y1[2 * i + 1]);
#pragma unroll
    for (int i = 0; i < 16; i++) ow[16 + i] = pack2(y2[2 * i], y2[2 * i + 1]);
    uint4* wp = (uint4*)row;
#pragma unroll
    for (int c = 0; c < 8; c++)
        wp[c] = make_uint4(ow[c * 4 + 0], ow[c * 4 + 1], ow[c * 4 + 2], ow[c * 4 + 3]);
}

// ---------------------------------------------------------------------------
// Kernel 3: causal flash attention, S^T formulation. Block = pair (px,31-px)
// of q-tiles (33 K-iters for every block). Per wave: 16 queries.
// S^T = K*Q^T via MFMA(kfrag, qfrag): C-layout col = QUERY, rows = keys, so
// softmax reduction over keys = in-lane tree over 16 regs + 2 shuffles
// (xor16/32), replacing the 32 serialized swizzles of the S formulation.
// exp2-domain (scale folded into Q). P^T packs to LDS as 4x ds_write_b64.
// ---------------------------------------------------------------------------
__global__ __launch_bounds__(256) void attn_kernel(
    const short* __restrict__ Q, const short* __restrict__ K,
    const short* __restrict__ VT, short* __restrict__ Y) {
    __shared__ __align__(16) short sQP[64 * LDP];   // Q during prologue, then P
    __shared__ __align__(16) short sK[64 * LDP];
    __shared__ __align__(16) short sVT[64 * LDP];

    const int tid = threadIdx.x;
    const int w = tid >> 6, lane = tid & 63, quad = lane >> 4, l15 = lane & 15;
    const int px = blockIdx.x;           // 0..15
    const int bh = blockIdx.y;           // 0..31
    const int b = bh >> 4, h = bh & 15;
    const short* Qp = Q + (size_t)bh * 2048 * 64;
    const short* Kp = K + (size_t)bh * 2048 * 64;
    const short* Vp = VT + (size_t)bh * 64 * 2048;   // [d][t]

    for (int pass = 0; pass < 2; pass++) {
        const int qt = pass ? (31 - px) : px;
        __syncthreads();                 // prior pass's sP readers done before Q reload
#pragma unroll
        for (int i = 0; i < 2; i++) {
            int p = tid + i * 256;       // 512 uint4 slots: 64 rows x 8
            int row = p >> 3, c8 = p & 7;
            uint4 v = *(const uint4*)(Qp + (size_t)(qt * 64 + row) * 64 + c8 * 8);
            *(uint4*)&sQP[row * LDP + c8 * 8] = v;
        }
        __syncthreads();
        s16x8 aq[2];
#pragma unroll
        for (int ks = 0; ks < 2; ks++)
            aq[ks] = *(const s16x8*)&sQP[(w * 16 + l15) * LDP + ks * 32 + quad * 8];

        f32x4 o[4];
#pragma unroll
        for (int i = 0; i < 4; i++) o[i] = f32x4{0.f, 0.f, 0.f, 0.f};
        float mrun = -INFINITY;          // per query (this lane's l15 column)
        float lrun = 0.f;
        const int q_idx = qt * 64 + w * 16 + l15;

        for (int kt = 0; kt <= qt; kt++) {
            __syncthreads();             // prior iter's sK/sVT readers done
#pragma unroll
            for (int i = 0; i < 2; i++) {
                int p = tid + i * 256;
                int row = p >> 3, c8 = p & 7;
                uint4 kv = *(const uint4*)(Kp + (size_t)(kt * 64 + row) * 64 + c8 * 8);
                *(uint4*)&sK[row * LDP + c8 * 8] = kv;
                uint4 vv = *(const uint4*)(Vp + (size_t)row * 2048 + kt * 64 + c8 * 8);
                *(uint4*)&sVT[row * LDP + c8 * 8] = vv;   // row = d, cols = keys
            }
            __syncthreads();

            // S^T tile: 64 keys x 16 queries per wave. A = K rows, B = Q^T.
            f32x4 sa[4];
#pragma unroll
            for (int i = 0; i < 4; i++) sa[i] = f32x4{0.f, 0.f, 0.f, 0.f};
#pragma unroll
            for (int ks = 0; ks < 2; ks++) {
#pragma unroll
                for (int ct = 0; ct < 4; ct++) {
                    s16x8 kf = *(const s16x8*)&sK[(ct * 16 + l15) * LDP + ks * 32 + quad * 8];
                    sa[ct] = MFMA16(kf, aq[ks], sa[ct]);
                }
            }

            // mask (keys this lane holds: kt*64 + ct*16 + quad*4 + r)
            const bool diag = (kt == qt);
            float ps[4][4];
#pragma unroll
            for (int ct = 0; ct < 4; ct++) {
                int kbase = kt * 64 + ct * 16 + quad * 4;
#pragma unroll
                for (int r = 0; r < 4; r++) {
                    float s = sa[ct][r];
                    if (diag && (kbase + r) > q_idx) s = -INFINITY;
                    ps[ct][r] = s;
                }
            }
            // max over this query's keys: in-lane tree + cross-quad xor16/32
            float cm[4];
#pragma unroll
            for (int ct = 0; ct < 4; ct++)
                cm[ct] = fmaxf(fmaxf(ps[ct][0], ps[ct][1]), fmaxf(ps[ct][2], ps[ct][3]));
            float mx = fmaxf(fmaxf(cm[0], cm[1]), fmaxf(cm[2], cm[3]));
            mx = fmaxf(mx, __shfl_xor(mx, 16));
            mx = fmaxf(mx, __shfl_xor(mx, 32));
            float mnew = fmaxf(mrun, mx);
            float alpha = exp2f(mrun - mnew);
            mrun = mnew;
            float cs[4];
#pragma unroll
            for (int ct = 0; ct < 4; ct++) {
#pragma unroll
                for (int r = 0; r < 4; r++) ps[ct][r] = exp2f(ps[ct][r] - mnew);
                cs[ct] = (ps[ct][0] + ps[ct][1]) + (ps[ct][2] + ps[ct][3]);
            }
            float psum = (cs[0] + cs[1]) + (cs[2] + cs[3]);
            psum += __shfl_xor(psum, 16);
            psum += __shfl_xor(psum, 32);
            lrun = lrun * alpha + psum;

            // broadcast alpha (per query l15) to O rows (query quad*4+r)
            float arow[4];
#pragma unroll
            for (int r = 0; r < 4; r++) arow[r] = __shfl(alpha, quad * 4 + r);
#pragma unroll
            for (int ct = 0; ct < 4; ct++)
#pragma unroll
                for (int r = 0; r < 4; r++) o[ct][r] *= arow[r];

            // P^T (C-layout) -> sP rows = query, packed 4 keys per ds_write_b64
#pragma unroll
            for (int ct = 0; ct < 4; ct++) {
                unsigned lo = pack2(ps[ct][0], ps[ct][1]);
                unsigned hi = pack2(ps[ct][2], ps[ct][3]);
                *(uint2*)&sQP[(w * 16 + l15) * LDP + ct * 16 + quad * 4] = make_uint2(lo, hi);
            }
            // no barrier: rows are wave-private, same-wave DS ops in-order

            // O += P V  (A = P rows=query, B = V^T)
#pragma unroll
            for (int ks2 = 0; ks2 < 2; ks2++) {
                s16x8 pa = *(const s16x8*)&sQP[(w * 16 + l15) * LDP + ks2 * 32 + quad * 8];
#pragma unroll
                for (int ct = 0; ct < 4; ct++) {
                    s16x8 vb = *(const s16x8*)&sVT[(ct * 16 + l15) * LDP + ks2 * 32 + quad * 8];
                    o[ct] = MFMA16(pa, vb, o[ct]);
                }
            }
        }

        // epilogue: normalize (lrun lives per query l15 -> bpermute to rows)
#pragma unroll
        for (int r = 0; r < 4; r++) {
            float linv = 1.0f / __shfl(lrun, quad * 4 + r);
            int t = qt * 64 + w * 16 + quad * 4 + r;
#pragma unroll
            for (int ct = 0; ct < 4; ct++) {
                float val = o[ct][r] * linv;
                Y[((size_t)(b * 2048 + t)) * 1024 + h * 64 + ct * 16 + l15] = f2bf(val);
            }
        }
    }
}

// ---------------------------------------------------------------------------
// Kernel 4: output projection, m97-structure. out[m,n] = sum_k Y[m,k]*Wo[n,k].
// M=4096, N=1024, K=1024, fp32 out.
// ---------------------------------------------------------------------------
__global__ __launch_bounds__(256) void oproj_kernel(
    const short* __restrict__ Yb, const short* __restrict__ Wob, float* __restrict__ out) {
    __shared__ __align__(16) short sA[128 * 64];
    __shared__ __align__(16) short sB[128 * 64];
    const int tid = threadIdx.x;
    const int w = tid >> 6, lane = tid & 63, quad = lane >> 4, l15 = lane & 15;
    const int wm = w & 1, wn = w >> 1;
    const int m0 = blockIdx.y * 128;
    const int nb = blockIdx.x * 128;

    f32x4 acc[4][4];
#pragma unroll
    for (int i = 0; i < 4; i++)
#pragma unroll
        for (int j = 0; j < 4; j++) acc[i][j] = f32x4{0.f, 0.f, 0.f, 0.f};

    for (int kb = 0; kb < 16; kb++) {
        const int k0 = kb * 64;
        if (kb) __syncthreads();
#pragma unroll
        for (int i = 0; i < 4; i++) {
            int c = i * 256 + tid;
            int row = c >> 3, col8 = (c & 7) * 8;
            async_ld16(Yb + (size_t)(m0 + row) * 1024 + k0 + col8,
                       &sA[(i * 256 + w * 64) * 8]);
            async_ld16(Wob + (size_t)(nb + row) * 1024 + k0 + col8,
                       &sB[(i * 256 + w * 64) * 8]);
        }
        __syncthreads();
#pragma unroll
        for (int ks = 0; ks < 2; ks++) {
            s16x8 av[4], bv[4];
#pragma unroll
            for (int at = 0; at < 4; at++)
                av[at] = *(const s16x8*)&sA[(wm * 64 + at * 16 + l15) * 64 + ks * 32 + quad * 8];
#pragma unroll
            for (int bt = 0; bt < 4; bt++)
                bv[bt] = *(const s16x8*)&sB[(wn * 64 + bt * 16 + l15) * 64 + ks * 32 + quad * 8];
#pragma unroll
            for (int at = 0; at < 4; at++)
#pragma unroll
                for (int bt = 0; bt < 4; bt++)
                    acc[at][bt] = MFMA16(av[at], bv[bt], acc[at][bt]);
        }
    }
#pragma unroll
    for (int at = 0; at < 4; at++)
#pragma unroll
        for (int r = 0; r < 4; r++) {
            int m = m0 + wm * 64 + at * 16 + quad * 4 + r;
#pragma unroll
            for (int bt = 0; bt < 4; bt++) {
                int n = nb + wn * 64 + bt * 16 + l15;
                out[(size_t)m * 1024 + n] = acc[at][bt][r];
            }
        }
}

extern "C" void kernel_launch(void* const* d_in, const int* in_sizes, int n_in,
                              void* d_out, int out_size, void* d_ws, size_t ws_size,
                              hipStream_t stream) {
    (void)in_sizes; (void)n_in; (void)out_size; (void)ws_size;
    const float* x  = (const float*)d_in[0];
    const float* Wq = (const float*)d_in[1];
    const float* Wk = (const float*)d_in[2];
    const float* Wv = (const float*)d_in[3];
    const float* Wo = (const float*)d_in[4];
    float* out = (float*)d_out;

    const size_t NE = (size_t)2 * 16 * 2048 * 64;   // 4M elems per tensor
    short* Q  = (short*)d_ws;
    short* K  = Q + NE;
    short* VT = K + NE;          // [B,H,D,T]
    short* Y  = VT + NE;         // attn output [B,T,C] bf16
    short* xb = Y;               // x bf16 ALIASES Y: consumed by qkv before attn writes Y
    short* wb = Y + NE;          // [Wq|Wk|Wv|Wo] bf16, 4M elems  (total ws = 40 MB)

    convert_kernel<<<4096, 256, 0, stream>>>(x, Wq, Wk, Wv, Wo, xb, wb);
    qkv_kernel<<<dim3(24, 32), 256, 0, stream>>>(xb, wb, Q, K, VT);
    rope_kernel<<<512, 256, 0, stream>>>(Q, K);
    attn_kernel<<<dim3(16, 32), 256, 0, stream>>>(Q, K, VT, Y);
    oproj_kernel<<<dim3(8, 32), 256, 0, stream>>>(Y, wb + 3 * 1048576, out);
}

// Round 4
// 217.685 us; speedup vs baseline: 1.9516x; 1.0899x over previous
//
#include <hip/hip_runtime.h>
#include <cstdint>
#include <cstddef>

typedef short s16x8 __attribute__((ext_vector_type(8)));
typedef float f32x4 __attribute__((ext_vector_type(4)));

#define MFMA16(a, b, c) __builtin_amdgcn_mfma_f32_16x16x32_bf16((a), (b), (c), 0, 0, 0)

constexpr int LDP = 72;  // padded LDS row stride for attn tiles (2-way bank alias = free)

__device__ __forceinline__ short f2bf(float f) {
    unsigned u = __builtin_bit_cast(unsigned, f);
    u += 0x7FFFu + ((u >> 16) & 1u);   // RNE
    return (short)(u >> 16);
}
__device__ __forceinline__ float bf2f(short s) {
    unsigned u = ((unsigned)(unsigned short)s) << 16;
    return __builtin_bit_cast(float, u);
}
__device__ __forceinline__ unsigned pack2(float a, float b) {
    return (unsigned)(unsigned short)f2bf(a) | ((unsigned)(unsigned short)f2bf(b) << 16);
}
// truncating pack (P in [0,1]: bias <= 1 bf16 ulp, ~0.2%) — saves VALU in hot loop
__device__ __forceinline__ unsigned pack2t(float a, float b) {
    unsigned ua = __builtin_bit_cast(unsigned, a);
    unsigned ub = __builtin_bit_cast(unsigned, b);
    return (ua >> 16) | (ub & 0xFFFF0000u);
}

// async 16B/lane global->LDS copy (global_load_lds_dwordx4). LDS dest must be
// wave-uniform base; HW adds lane*16.
__device__ __forceinline__ void async_ld16(const void* g, void* l) {
    __builtin_amdgcn_global_load_lds(
        (const __attribute__((address_space(1))) unsigned int*)g,
        (__attribute__((address_space(3))) unsigned int*)l, 16, 0, 0);
}

// ---------------------------------------------------------------------------
// Kernel 0: fp32 -> bf16 convert of x and all four weights (once per call).
// ---------------------------------------------------------------------------
__global__ __launch_bounds__(256) void convert_kernel(
    const float* __restrict__ x, const float* __restrict__ Wq,
    const float* __restrict__ Wk, const float* __restrict__ Wv,
    const float* __restrict__ Wo, short* __restrict__ xb, short* __restrict__ wb) {
    const size_t f = ((size_t)blockIdx.x * 256 + threadIdx.x) * 8;   // 8 floats/thread
    const float* src;
    short* dst;
    if (f < 4194304) { src = x + f; dst = xb + f; }
    else {
        size_t wo = f - 4194304;
        int seg = (int)(wo >> 20);
        const float* ws4[4] = {Wq, Wk, Wv, Wo};
        src = ws4[seg] + (wo & 1048575u);
        dst = wb + wo;
    }
    float4 a = ((const float4*)src)[0];
    float4 b = ((const float4*)src)[1];
    *(uint4*)dst = make_uint4(pack2(a.x, a.y), pack2(a.z, a.w),
                              pack2(b.x, b.y), pack2(b.z, b.w));
}

// ---------------------------------------------------------------------------
// Kernel 1: QKV projection, m97-structure (128x128 tile, BK=64, async stage).
// Q,K -> [B,H,T,D] bf16; V -> [B,H,D,T] bf16 (pre-transposed).
// ---------------------------------------------------------------------------
__global__ __launch_bounds__(256) void qkv_kernel(
    const short* __restrict__ xb, const short* __restrict__ wb,
    short* __restrict__ Qo, short* __restrict__ Ko, short* __restrict__ VTo) {
    __shared__ __align__(16) short sA[128 * 64];
    __shared__ __align__(16) short sB[128 * 64];
    const int tid = threadIdx.x;
    const int w = tid >> 6, lane = tid & 63, quad = lane >> 4, l15 = lane & 15;
    const int wm = w & 1, wn = w >> 1;
    const int bx = blockIdx.x, by = blockIdx.y;
    const int m0 = by * 128;
    const int nb = bx * 128;

    f32x4 acc[4][4];
#pragma unroll
    for (int i = 0; i < 4; i++)
#pragma unroll
        for (int j = 0; j < 4; j++) acc[i][j] = f32x4{0.f, 0.f, 0.f, 0.f};

    for (int kb = 0; kb < 16; kb++) {
        const int k0 = kb * 64;
        if (kb) __syncthreads();
#pragma unroll
        for (int i = 0; i < 4; i++) {
            int c = i * 256 + tid;             // 16B chunk id
            int row = c >> 3, col8 = (c & 7) * 8;
            async_ld16(xb + (size_t)(m0 + row) * 1024 + k0 + col8,
                       &sA[(i * 256 + w * 64) * 8]);
            async_ld16(wb + (size_t)(nb + row) * 1024 + k0 + col8,
                       &sB[(i * 256 + w * 64) * 8]);
        }
        __syncthreads();
#pragma unroll
        for (int ks = 0; ks < 2; ks++) {
            s16x8 av[4], bv[4];
#pragma unroll
            for (int at = 0; at < 4; at++)
                av[at] = *(const s16x8*)&sA[(wm * 64 + at * 16 + l15) * 64 + ks * 32 + quad * 8];
#pragma unroll
            for (int bt = 0; bt < 4; bt++)
                bv[bt] = *(const s16x8*)&sB[(wn * 64 + bt * 16 + l15) * 64 + ks * 32 + quad * 8];
#pragma unroll
            for (int at = 0; at < 4; at++)
#pragma unroll
                for (int bt = 0; bt < 4; bt++)
                    acc[at][bt] = MFMA16(av[at], bv[bt], acc[at][bt]);
        }
    }

    const int wsel = bx >> 3;                 // 0=q 1=k 2=v
    const int h = (bx & 7) * 2 + wn;          // head (uniform per wave)
    if (wsel == 2) {
#pragma unroll
        for (int at = 0; at < 4; at++) {
            int m = m0 + wm * 64 + at * 16 + quad * 4;
            int b = m >> 11, t0 = m & 2047;
            size_t base = ((size_t)((b * 16 + h) * 64)) * 2048;
#pragma unroll
            for (int bt = 0; bt < 4; bt++) {
                int d = bt * 16 + l15;
                unsigned lo = pack2(acc[at][bt][0], acc[at][bt][1]);
                unsigned hi = pack2(acc[at][bt][2], acc[at][bt][3]);
                *(uint2*)&VTo[base + (size_t)d * 2048 + t0] = make_uint2(lo, hi);
            }
        }
    } else {
        short* Out = (wsel == 0) ? Qo : Ko;
#pragma unroll
        for (int at = 0; at < 4; at++)
#pragma unroll
            for (int r = 0; r < 4; r++) {
                int m = m0 + wm * 64 + at * 16 + quad * 4 + r;
                int b = m >> 11, t = m & 2047;
                size_t base = (((size_t)(b * 16 + h)) * 2048 + t) * 64;
#pragma unroll
                for (int bt = 0; bt < 4; bt++)
                    Out[base + bt * 16 + l15] = f2bf(acc[at][bt][r]);
            }
    }
}

// ---------------------------------------------------------------------------
// Kernel 2: RoPE in-place on Q and K. Q pre-scaled by 0.125*log2(e) (exp2
// domain softmax).
// ---------------------------------------------------------------------------
__global__ __launch_bounds__(256) void rope_kernel(short* __restrict__ Q, short* __restrict__ K) {
    const int rid = blockIdx.x * 256 + threadIdx.x;   // 0..131071
    const bool isK = (rid & 65536) != 0;
    short* buf = isK ? K : Q;
    const float sc = isK ? 1.0f : 0.18033688011112042f;   // 1/8 * log2(e)
    const int r2 = rid & 65535;          // bh*2048 + t
    const int t = r2 & 2047;
    short* row = buf + (size_t)r2 * 64;

    unsigned wv[32];
    const uint4* rp = (const uint4*)row;
#pragma unroll
    for (int c = 0; c < 8; c++) {
        uint4 v = rp[c];
        wv[c * 4 + 0] = v.x; wv[c * 4 + 1] = v.y; wv[c * 4 + 2] = v.z; wv[c * 4 + 3] = v.w;
    }
    float y1[32], y2[32];
    const float tf = (float)t;
#pragma unroll
    for (int i = 0; i < 32; i++) {
        float x1 = bf2f((short)(wv[i] & 0xFFFFu));
        float x2 = bf2f((short)(wv[i] >> 16));
        float inv = expf(-9.2103403719761836f * (float)i * (1.0f / 32.0f));  // 10000^(-i/32)
        float fr = tf * inv;
        float sn, cs;
        sincosf(fr, &sn, &cs);
        y1[i] = (x1 * cs - x2 * sn) * sc;
        y2[i] = (x1 * sn + x2 * cs) * sc;
    }
    unsigned ow[32];
#pragma unroll
    for (int i = 0; i < 16; i++) ow[i] = pack2(y1[2 * i], y1[2 * i + 1]);
#pragma unroll
    for (int i = 0; i < 16; i++) ow[16 + i] = pack2(y2[2 * i], y2[2 * i + 1]);
    uint4* wp = (uint4*)row;
#pragma unroll
    for (int c = 0; c < 8; c++)
        wp[c] = make_uint4(ow[c * 4 + 0], ow[c * 4 + 1], ow[c * 4 + 2], ow[c * 4 + 3]);
}

// ---------------------------------------------------------------------------
// Kernel 3: causal flash attention, KEY-SPLIT partials. Unit = (qt, chunk of
// 8 K-tiles). 80 units per bh -> grid 80x32 = 2560 blocks (~10/CU queued,
// 5 resident on LDS). Each unit runs <=8 iterations of the S^T inner loop and
// writes UNNORMALIZED partial O (bf16) + m,l (fp32); combine_kernel merges.
// Units dispatched largest-first (u = 79-bx).
// ---------------------------------------------------------------------------
__global__ __launch_bounds__(256) void attn_kernel(
    const short* __restrict__ Q, const short* __restrict__ K,
    const short* __restrict__ VT, short* __restrict__ paO, float* __restrict__ ml) {
    __shared__ __align__(16) short sQP[64 * LDP];   // Q during prologue, then P
    __shared__ __align__(16) short sK[64 * LDP];
    __shared__ __align__(16) short sVT[64 * LDP];

    const int tid = threadIdx.x;
    const int w = tid >> 6, lane = tid & 63, quad = lane >> 4, l15 = lane & 15;
    const int u = 79 - blockIdx.x;       // largest-qt units first
    const int bh = blockIdx.y;           // 0..31

    int qt, c;
    if (u < 8)       { qt = u; c = 0; }
    else if (u < 24) { int v = u - 8;  qt = 8 + (v >> 1); c = v & 1; }
    else if (u < 48) { int v = u - 24; qt = 16 + v / 3;   c = v - 3 * (qt - 16); }
    else             { int v = u - 48; qt = 24 + (v >> 2); c = v & 3; }
    const int kt0 = c * 8;
    const int kt1 = min(kt0 + 7, qt);

    const short* Qp = Q + (size_t)bh * 2048 * 64;
    const short* Kp = K + (size_t)bh * 2048 * 64;
    const short* Vp = VT + (size_t)bh * 64 * 2048;   // [d][t]

    // stage Q tile (64 rows x 64 dims)
#pragma unroll
    for (int i = 0; i < 2; i++) {
        int p = tid + i * 256;       // 512 uint4 slots: 64 rows x 8
        int row = p >> 3, c8 = p & 7;
        uint4 v = *(const uint4*)(Qp + (size_t)(qt * 64 + row) * 64 + c8 * 8);
        *(uint4*)&sQP[row * LDP + c8 * 8] = v;
    }
    __syncthreads();
    s16x8 aq[2];
#pragma unroll
    for (int ks = 0; ks < 2; ks++)
        aq[ks] = *(const s16x8*)&sQP[(w * 16 + l15) * LDP + ks * 32 + quad * 8];

    f32x4 o[4];
#pragma unroll
    for (int i = 0; i < 4; i++) o[i] = f32x4{0.f, 0.f, 0.f, 0.f};
    float mrun = -INFINITY;          // per query (this lane's l15 column)
    float lrun = 0.f;
    const int q_idx = qt * 64 + w * 16 + l15;

    for (int kt = kt0; kt <= kt1; kt++) {
        __syncthreads();             // prior iter's sK/sVT readers done (covers aq reads iter 0)
#pragma unroll
        for (int i = 0; i < 2; i++) {
            int p = tid + i * 256;
            int row = p >> 3, c8 = p & 7;
            uint4 kv = *(const uint4*)(Kp + (size_t)(kt * 64 + row) * 64 + c8 * 8);
            *(uint4*)&sK[row * LDP + c8 * 8] = kv;
            uint4 vv = *(const uint4*)(Vp + (size_t)row * 2048 + kt * 64 + c8 * 8);
            *(uint4*)&sVT[row * LDP + c8 * 8] = vv;   // row = d, cols = keys
        }
        __syncthreads();

        // S^T tile: 64 keys x 16 queries per wave. A = K rows, B = Q^T.
        f32x4 sa[4];
#pragma unroll
        for (int i = 0; i < 4; i++) sa[i] = f32x4{0.f, 0.f, 0.f, 0.f};
#pragma unroll
        for (int ks = 0; ks < 2; ks++) {
#pragma unroll
            for (int ct = 0; ct < 4; ct++) {
                s16x8 kf = *(const s16x8*)&sK[(ct * 16 + l15) * LDP + ks * 32 + quad * 8];
                sa[ct] = MFMA16(kf, aq[ks], sa[ct]);
            }
        }

        // mask (keys this lane holds: kt*64 + ct*16 + quad*4 + r)
        const bool diag = (kt == qt);
        float ps[4][4];
#pragma unroll
        for (int ct = 0; ct < 4; ct++) {
            int kbase = kt * 64 + ct * 16 + quad * 4;
#pragma unroll
            for (int r = 0; r < 4; r++) {
                float s = sa[ct][r];
                if (diag && (kbase + r) > q_idx) s = -INFINITY;
                ps[ct][r] = s;
            }
        }
        // max over this query's keys: in-lane tree + cross-quad xor16/32
        float cm[4];
#pragma unroll
        for (int ct = 0; ct < 4; ct++)
            cm[ct] = fmaxf(fmaxf(ps[ct][0], ps[ct][1]), fmaxf(ps[ct][2], ps[ct][3]));
        float mx = fmaxf(fmaxf(cm[0], cm[1]), fmaxf(cm[2], cm[3]));
        mx = fmaxf(mx, __shfl_xor(mx, 16));
        mx = fmaxf(mx, __shfl_xor(mx, 32));
        float mnew = fmaxf(mrun, mx);
        float alpha = exp2f(mrun - mnew);
        mrun = mnew;
        float cs[4];
#pragma unroll
        for (int ct = 0; ct < 4; ct++) {
#pragma unroll
            for (int r = 0; r < 4; r++) ps[ct][r] = exp2f(ps[ct][r] - mnew);
            cs[ct] = (ps[ct][0] + ps[ct][1]) + (ps[ct][2] + ps[ct][3]);
        }
        float psum = (cs[0] + cs[1]) + (cs[2] + cs[3]);
        psum += __shfl_xor(psum, 16);
        psum += __shfl_xor(psum, 32);
        lrun = lrun * alpha + psum;

        // broadcast alpha (per query l15) to O rows (query quad*4+r)
        float arow[4];
#pragma unroll
        for (int r = 0; r < 4; r++) arow[r] = __shfl(alpha, quad * 4 + r);
#pragma unroll
        for (int ct = 0; ct < 4; ct++)
#pragma unroll
            for (int r = 0; r < 4; r++) o[ct][r] *= arow[r];

        // P^T (C-layout) -> sP rows = query, packed 4 keys per ds_write_b64
#pragma unroll
        for (int ct = 0; ct < 4; ct++) {
            unsigned lo = pack2t(ps[ct][0], ps[ct][1]);
            unsigned hi = pack2t(ps[ct][2], ps[ct][3]);
            *(uint2*)&sQP[(w * 16 + l15) * LDP + ct * 16 + quad * 4] = make_uint2(lo, hi);
        }
        // no barrier: rows are wave-private, same-wave DS ops in-order

        // O += P V  (A = P rows=query, B = V^T)
#pragma unroll
        for (int ks2 = 0; ks2 < 2; ks2++) {
            s16x8 pa = *(const s16x8*)&sQP[(w * 16 + l15) * LDP + ks2 * 32 + quad * 8];
#pragma unroll
            for (int ct = 0; ct < 4; ct++) {
                s16x8 vb = *(const s16x8*)&sVT[(ct * 16 + l15) * LDP + ks2 * 32 + quad * 8];
                o[ct] = MFMA16(pa, vb, o[ct]);
            }
        }
    }

    // epilogue: UNNORMALIZED partial O (bf16), m/l (fp32, per query row)
    const size_t pbase = ((size_t)(bh * 80 + u)) * 4096;
#pragma unroll
    for (int r = 0; r < 4; r++) {
        int row = w * 16 + quad * 4 + r;
#pragma unroll
        for (int ct = 0; ct < 4; ct++)
            paO[pbase + row * 64 + ct * 16 + l15] = f2bf(o[ct][r]);
    }
    if (quad == 0) {
        int mlbase = (bh * 80 + u) * 128;
        ml[mlbase + w * 16 + l15] = mrun;
        ml[mlbase + 64 + w * 16 + l15] = lrun;
    }
}

// ---------------------------------------------------------------------------
// Kernel 3b: combine partials. Block = (qt, bh); merges nch = qt/8+1 partials:
// M = max m_i; L = sum l_i*2^(m_i-M); Y = sum O_i*2^(m_i-M) / L.
// Thread owns (row = tid>>2, 16 cols at (tid&3)*16).
// ---------------------------------------------------------------------------
__global__ __launch_bounds__(256) void combine_kernel(
    const short* __restrict__ paO, const float* __restrict__ ml, short* __restrict__ Y) {
    const int qt = blockIdx.x, bh = blockIdx.y;
    const int b = bh >> 4, h = bh & 15;
    const int nch = (qt >> 3) + 1;
    int base;
    if (qt < 8) base = qt;
    else if (qt < 16) base = 8 + 2 * (qt - 8);
    else if (qt < 24) base = 24 + 3 * (qt - 16);
    else base = 48 + 4 * (qt - 24);

    const int row = threadIdx.x >> 2;
    const int cq = (threadIdx.x & 3) * 16;

    float mi[4], li[4];
    float M = -INFINITY;
    for (int i = 0; i < nch; i++) {
        int mlbase = (bh * 80 + base + i) * 128;
        mi[i] = ml[mlbase + row];
        li[i] = ml[mlbase + 64 + row];
        M = fmaxf(M, mi[i]);
    }
    float L = 0.f, ai[4];
    for (int i = 0; i < nch; i++) {
        ai[i] = exp2f(mi[i] - M);
        L += li[i] * ai[i];
    }
    const float inv = 1.0f / L;

    float acc[16];
#pragma unroll
    for (int j = 0; j < 16; j++) acc[j] = 0.f;
    for (int i = 0; i < nch; i++) {
        const short* p = paO + ((size_t)(bh * 80 + base + i)) * 4096 + row * 64 + cq;
        uint4 v0 = ((const uint4*)p)[0];
        uint4 v1 = ((const uint4*)p)[1];
        unsigned vs[8] = {v0.x, v0.y, v0.z, v0.w, v1.x, v1.y, v1.z, v1.w};
#pragma unroll
        for (int j = 0; j < 8; j++) {
            acc[2 * j + 0] += bf2f((short)(vs[j] & 0xFFFFu)) * ai[i];
            acc[2 * j + 1] += bf2f((short)(vs[j] >> 16)) * ai[i];
        }
    }
    const int t = qt * 64 + row;
    short* yp = Y + ((size_t)(b * 2048 + t)) * 1024 + h * 64 + cq;
    unsigned ow[8];
#pragma unroll
    for (int j = 0; j < 8; j++) ow[j] = pack2(acc[2 * j] * inv, acc[2 * j + 1] * inv);
    ((uint4*)yp)[0] = make_uint4(ow[0], ow[1], ow[2], ow[3]);
    ((uint4*)yp)[1] = make_uint4(ow[4], ow[5], ow[6], ow[7]);
}

// ---------------------------------------------------------------------------
// Kernel 4: output projection, m97-structure. fp32 out.
// ---------------------------------------------------------------------------
__global__ __launch_bounds__(256) void oproj_kernel(
    const short* __restrict__ Yb, const short* __restrict__ Wob, float* __restrict__ out) {
    __shared__ __align__(16) short sA[128 * 64];
    __shared__ __align__(16) short sB[128 * 64];
    const int tid = threadIdx.x;
    const int w = tid >> 6, lane = tid & 63, quad = lane >> 4, l15 = lane & 15;
    const int wm = w & 1, wn = w >> 1;
    const int m0 = blockIdx.y * 128;
    const int nb = blockIdx.x * 128;

    f32x4 acc[4][4];
#pragma unroll
    for (int i = 0; i < 4; i++)
#pragma unroll
        for (int j = 0; j < 4; j++) acc[i][j] = f32x4{0.f, 0.f, 0.f, 0.f};

    for (int kb = 0; kb < 16; kb++) {
        const int k0 = kb * 64;
        if (kb) __syncthreads();
#pragma unroll
        for (int i = 0; i < 4; i++) {
            int c = i * 256 + tid;
            int row = c >> 3, col8 = (c & 7) * 8;
            async_ld16(Yb + (size_t)(m0 + row) * 1024 + k0 + col8,
                       &sA[(i * 256 + w * 64) * 8]);
            async_ld16(Wob + (size_t)(nb + row) * 1024 + k0 + col8,
                       &sB[(i * 256 + w * 64) * 8]);
        }
        __syncthreads();
#pragma unroll
        for (int ks = 0; ks < 2; ks++) {
            s16x8 av[4], bv[4];
#pragma unroll
            for (int at = 0; at < 4; at++)
                av[at] = *(const s16x8*)&sA[(wm * 64 + at * 16 + l15) * 64 + ks * 32 + quad * 8];
#pragma unroll
            for (int bt = 0; bt < 4; bt++)
                bv[bt] = *(const s16x8*)&sB[(wn * 64 + bt * 16 + l15) * 64 + ks * 32 + quad * 8];
#pragma unroll
            for (int at = 0; at < 4; at++)
#pragma unroll
                for (int bt = 0; bt < 4; bt++)
                    acc[at][bt] = MFMA16(av[at], bv[bt], acc[at][bt]);
        }
    }
#pragma unroll
    for (int at = 0; at < 4; at++)
#pragma unroll
        for (int r = 0; r < 4; r++) {
            int m = m0 + wm * 64 + at * 16 + quad * 4 + r;
#pragma unroll
            for (int bt = 0; bt < 4; bt++) {
                int n = nb + wn * 64 + bt * 16 + l15;
                out[(size_t)m * 1024 + n] = acc[at][bt][r];
            }
        }
}

extern "C" void kernel_launch(void* const* d_in, const int* in_sizes, int n_in,
                              void* d_out, int out_size, void* d_ws, size_t ws_size,
                              hipStream_t stream) {
    (void)in_sizes; (void)n_in; (void)out_size; (void)ws_size;
    const float* x  = (const float*)d_in[0];
    const float* Wq = (const float*)d_in[1];
    const float* Wk = (const float*)d_in[2];
    const float* Wv = (const float*)d_in[3];
    const float* Wo = (const float*)d_in[4];
    float* out = (float*)d_out;

    const size_t NE = (size_t)2 * 16 * 2048 * 64;   // 4M elems per tensor
    short* Q   = (short*)d_ws;
    short* K   = Q + NE;
    short* VT  = K + NE;          // [B,H,D,T]
    short* Y   = VT + NE;         // attn output [B,T,C] bf16
    short* xb  = Y;               // x bf16 ALIASES Y: consumed by qkv before combine writes Y
    short* wb  = Y + NE;          // [Wq|Wk|Wv|Wo] bf16, 4M elems
    short* paO = wb + NE;         // partial O: 32 bh x 80 units x 64x64 bf16 = 21 MB
    float* ml  = (float*)(paO + (size_t)32 * 80 * 4096);   // m,l: 32x80x128 fp32

    convert_kernel<<<4096, 256, 0, stream>>>(x, Wq, Wk, Wv, Wo, xb, wb);
    qkv_kernel<<<dim3(24, 32), 256, 0, stream>>>(xb, wb, Q, K, VT);
    rope_kernel<<<512, 256, 0, stream>>>(Q, K);
    attn_kernel<<<dim3(80, 32), 256, 0, stream>>>(Q, K, VT, paO, ml);
    combine_kernel<<<dim3(32, 32), 256, 0, stream>>>(paO, ml, Y);
    oproj_kernel<<<dim3(8, 32), 256, 0, stream>>>(Y, wb + 3 * 1048576, out);
}

// Round 5
// 211.733 us; speedup vs baseline: 2.0065x; 1.0281x over previous
//
#include <hip/hip_runtime.h>
#include <cstdint>
#include <cstddef>

typedef short s16x8 __attribute__((ext_vector_type(8)));
typedef float f32x4 __attribute__((ext_vector_type(4)));

#define MFMA16(a, b, c) __builtin_amdgcn_mfma_f32_16x16x32_bf16((a), (b), (c), 0, 0, 0)

constexpr int LDP = 72;  // padded LDS row stride for attn tiles (2-way bank alias = free)

__device__ __forceinline__ short f2bf(float f) {
    unsigned u = __builtin_bit_cast(unsigned, f);
    u += 0x7FFFu + ((u >> 16) & 1u);   // RNE
    return (short)(u >> 16);
}
__device__ __forceinline__ float bf2f(short s) {
    unsigned u = ((unsigned)(unsigned short)s) << 16;
    return __builtin_bit_cast(float, u);
}
__device__ __forceinline__ unsigned pack2(float a, float b) {
    return (unsigned)(unsigned short)f2bf(a) | ((unsigned)(unsigned short)f2bf(b) << 16);
}
// truncating pack (P in [0,1]: bias <= 1 bf16 ulp) — saves VALU in hot loop
__device__ __forceinline__ unsigned pack2t(float a, float b) {
    unsigned ua = __builtin_bit_cast(unsigned, a);
    unsigned ub = __builtin_bit_cast(unsigned, b);
    return (ua >> 16) | (ub & 0xFFFF0000u);
}

// async 16B/lane global->LDS copy (global_load_lds_dwordx4). LDS dest must be
// wave-uniform base; HW adds lane*16.
__device__ __forceinline__ void async_ld16(const void* g, void* l) {
    __builtin_amdgcn_global_load_lds(
        (const __attribute__((address_space(1))) unsigned int*)g,
        (__attribute__((address_space(3))) unsigned int*)l, 16, 0, 0);
}

// ---------------------------------------------------------------------------
// Kernel 0: fp32 -> bf16 convert of x and all four weights (once per call).
// ---------------------------------------------------------------------------
__global__ __launch_bounds__(256) void convert_kernel(
    const float* __restrict__ x, const float* __restrict__ Wq,
    const float* __restrict__ Wk, const float* __restrict__ Wv,
    const float* __restrict__ Wo, short* __restrict__ xb, short* __restrict__ wb) {
    const size_t f = ((size_t)blockIdx.x * 256 + threadIdx.x) * 8;   // 8 floats/thread
    const float* src;
    short* dst;
    if (f < 4194304) { src = x + f; dst = xb + f; }
    else {
        size_t wo = f - 4194304;
        int seg = (int)(wo >> 20);
        const float* ws4[4] = {Wq, Wk, Wv, Wo};
        src = ws4[seg] + (wo & 1048575u);
        dst = wb + wo;
    }
    float4 a = ((const float4*)src)[0];
    float4 b = ((const float4*)src)[1];
    *(uint4*)dst = make_uint4(pack2(a.x, a.y), pack2(a.z, a.w),
                              pack2(b.x, b.y), pack2(b.z, b.w));
}

// ---------------------------------------------------------------------------
// Kernel 1: QKV projection, m97-structure (128x128 tile, BK=64, async stage).
// Q,K -> [B,H,T,D] bf16; V -> [B,H,D,T] bf16 (pre-transposed).
// ---------------------------------------------------------------------------
__global__ __launch_bounds__(256) void qkv_kernel(
    const short* __restrict__ xb, const short* __restrict__ wb,
    short* __restrict__ Qo, short* __restrict__ Ko, short* __restrict__ VTo) {
    __shared__ __align__(16) short sA[128 * 64];
    __shared__ __align__(16) short sB[128 * 64];
    const int tid = threadIdx.x;
    const int w = tid >> 6, lane = tid & 63, quad = lane >> 4, l15 = lane & 15;
    const int wm = w & 1, wn = w >> 1;
    const int bx = blockIdx.x, by = blockIdx.y;
    const int m0 = by * 128;
    const int nb = bx * 128;

    f32x4 acc[4][4];
#pragma unroll
    for (int i = 0; i < 4; i++)
#pragma unroll
        for (int j = 0; j < 4; j++) acc[i][j] = f32x4{0.f, 0.f, 0.f, 0.f};

    for (int kb = 0; kb < 16; kb++) {
        const int k0 = kb * 64;
        if (kb) __syncthreads();
#pragma unroll
        for (int i = 0; i < 4; i++) {
            int c = i * 256 + tid;             // 16B chunk id
            int row = c >> 3, col8 = (c & 7) * 8;
            async_ld16(xb + (size_t)(m0 + row) * 1024 + k0 + col8,
                       &sA[(i * 256 + w * 64) * 8]);
            async_ld16(wb + (size_t)(nb + row) * 1024 + k0 + col8,
                       &sB[(i * 256 + w * 64) * 8]);
        }
        __syncthreads();
#pragma unroll
        for (int ks = 0; ks < 2; ks++) {
            s16x8 av[4], bv[4];
#pragma unroll
            for (int at = 0; at < 4; at++)
                av[at] = *(const s16x8*)&sA[(wm * 64 + at * 16 + l15) * 64 + ks * 32 + quad * 8];
#pragma unroll
            for (int bt = 0; bt < 4; bt++)
                bv[bt] = *(const s16x8*)&sB[(wn * 64 + bt * 16 + l15) * 64 + ks * 32 + quad * 8];
#pragma unroll
            for (int at = 0; at < 4; at++)
#pragma unroll
                for (int bt = 0; bt < 4; bt++)
                    acc[at][bt] = MFMA16(av[at], bv[bt], acc[at][bt]);
        }
    }

    const int wsel = bx >> 3;                 // 0=q 1=k 2=v
    const int h = (bx & 7) * 2 + wn;          // head (uniform per wave)
    if (wsel == 2) {
#pragma unroll
        for (int at = 0; at < 4; at++) {
            int m = m0 + wm * 64 + at * 16 + quad * 4;
            int b = m >> 11, t0 = m & 2047;
            size_t base = ((size_t)((b * 16 + h) * 64)) * 2048;
#pragma unroll
            for (int bt = 0; bt < 4; bt++) {
                int d = bt * 16 + l15;
                unsigned lo = pack2(acc[at][bt][0], acc[at][bt][1]);
                unsigned hi = pack2(acc[at][bt][2], acc[at][bt][3]);
                *(uint2*)&VTo[base + (size_t)d * 2048 + t0] = make_uint2(lo, hi);
            }
        }
    } else {
        short* Out = (wsel == 0) ? Qo : Ko;
#pragma unroll
        for (int at = 0; at < 4; at++)
#pragma unroll
            for (int r = 0; r < 4; r++) {
                int m = m0 + wm * 64 + at * 16 + quad * 4 + r;
                int b = m >> 11, t = m & 2047;
                size_t base = (((size_t)(b * 16 + h)) * 2048 + t) * 64;
#pragma unroll
                for (int bt = 0; bt < 4; bt++)
                    Out[base + bt * 16 + l15] = f2bf(acc[at][bt][r]);
            }
    }
}

// ---------------------------------------------------------------------------
// Kernel 2: RoPE in-place on Q and K. Q pre-scaled by 0.125*log2(e) (exp2
// domain softmax). Native v_sin/v_cos (revolutions) replace libm sincosf —
// phase err <= 2.4e-4 rad at fr<=2048, far below bf16 quantum.
// ---------------------------------------------------------------------------
__global__ __launch_bounds__(256) void rope_kernel(short* __restrict__ Q, short* __restrict__ K) {
    const int rid = blockIdx.x * 256 + threadIdx.x;   // 0..131071
    const bool isK = (rid & 65536) != 0;
    short* buf = isK ? K : Q;
    const float sc = isK ? 1.0f : 0.18033688011112042f;   // 1/8 * log2(e)
    const int r2 = rid & 65535;          // bh*2048 + t
    const int t = r2 & 2047;
    short* row = buf + (size_t)r2 * 64;

    unsigned wv[32];
    const uint4* rp = (const uint4*)row;
#pragma unroll
    for (int c = 0; c < 8; c++) {
        uint4 v = rp[c];
        wv[c * 4 + 0] = v.x; wv[c * 4 + 1] = v.y; wv[c * 4 + 2] = v.z; wv[c * 4 + 3] = v.w;
    }
    float y1[32], y2[32];
    const float tf = (float)t;
#pragma unroll
    for (int i = 0; i < 32; i++) {
        float x1 = bf2f((short)(wv[i] & 0xFFFFu));
        float x2 = bf2f((short)(wv[i] >> 16));
        float inv = exp2f((float)i * -0.4152410118609203f);  // 10000^(-i/32), const-folded
        float rev = tf * inv * 0.15915494309189535f;         // fr / 2pi
        rev = rev - floorf(rev);
        float sn = __builtin_amdgcn_sinf(rev);               // sin(rev*2pi) = sin(fr)
        float cs = __builtin_amdgcn_cosf(rev);
        y1[i] = (x1 * cs - x2 * sn) * sc;
        y2[i] = (x1 * sn + x2 * cs) * sc;
    }
    unsigned ow[32];
#pragma unroll
    for (int i = 0; i < 16; i++) ow[i] = pack2(y1[2 * i], y1[2 * i + 1]);
#pragma unroll
    for (int i = 0; i < 16; i++) ow[16 + i] = pack2(y2[2 * i], y2[2 * i + 1]);
    uint4* wp = (uint4*)row;
#pragma unroll
    for (int c = 0; c < 8; c++)
        wp[c] = make_uint4(ow[c * 4 + 0], ow[c * 4 + 1], ow[c * 4 + 2], ow[c * 4 + 3]);
}

// ---------------------------------------------------------------------------
// Kernel 3: causal flash attention, KEY-SPLIT partials + REGISTER PREFETCH.
// Unit = (qt, chunk of 8 K-tiles); 80 units/bh, grid 80x32. Per iteration:
// barrier -> ds_write prefetched K/V regs -> issue loads for kt+1 -> barrier
// -> MFMA+softmax. The global-load latency overlaps the compute phase instead
// of sitting between the barriers. Causal mask applies only when kt==qt
// (uniform branch; skipped by s_cbranch on 7/8 iterations).
// ---------------------------------------------------------------------------
__global__ __launch_bounds__(256) void attn_kernel(
    const short* __restrict__ Q, const short* __restrict__ K,
    const short* __restrict__ VT, short* __restrict__ paO, float* __restrict__ ml) {
    __shared__ __align__(16) short sQP[64 * LDP];   // Q during prologue, then P
    __shared__ __align__(16) short sK[64 * LDP];
    __shared__ __align__(16) short sVT[64 * LDP];

    const int tid = threadIdx.x;
    const int w = tid >> 6, lane = tid & 63, quad = lane >> 4, l15 = lane & 15;
    const int u = 79 - blockIdx.x;       // largest-qt units first
    const int bh = blockIdx.y;           // 0..31

    int qt, c;
    if (u < 8)       { qt = u; c = 0; }
    else if (u < 24) { int v = u - 8;  qt = 8 + (v >> 1); c = v & 1; }
    else if (u < 48) { int v = u - 24; qt = 16 + v / 3;   c = v - 3 * (qt - 16); }
    else             { int v = u - 48; qt = 24 + (v >> 2); c = v & 3; }
    const int kt0 = c * 8;
    const int kt1 = min(kt0 + 7, qt);

    const short* Qp = Q + (size_t)bh * 2048 * 64;
    const short* Kp = K + (size_t)bh * 2048 * 64;
    const short* Vp = VT + (size_t)bh * 64 * 2048;   // [d][t]

    // per-thread staging slot (two uint4 each for K and V per tile)
    const int ro = tid >> 3, co = (tid & 7) * 8;

    // prefetch tile kt0 into regs
    uint4 rK0 = *(const uint4*)(Kp + (size_t)(kt0 * 64 + ro) * 64 + co);
    uint4 rK1 = *(const uint4*)(Kp + (size_t)(kt0 * 64 + ro + 32) * 64 + co);
    uint4 rV0 = *(const uint4*)(Vp + (size_t)ro * 2048 + kt0 * 64 + co);
    uint4 rV1 = *(const uint4*)(Vp + (size_t)(ro + 32) * 2048 + kt0 * 64 + co);

    // stage Q tile (64 rows x 64 dims)
#pragma unroll
    for (int i = 0; i < 2; i++) {
        int p = tid + i * 256;       // 512 uint4 slots: 64 rows x 8
        int row = p >> 3, c8 = p & 7;
        uint4 v = *(const uint4*)(Qp + (size_t)(qt * 64 + row) * 64 + c8 * 8);
        *(uint4*)&sQP[row * LDP + c8 * 8] = v;
    }
    __syncthreads();
    s16x8 aq[2];
#pragma unroll
    for (int ks = 0; ks < 2; ks++)
        aq[ks] = *(const s16x8*)&sQP[(w * 16 + l15) * LDP + ks * 32 + quad * 8];

    f32x4 o[4];
#pragma unroll
    for (int i = 0; i < 4; i++) o[i] = f32x4{0.f, 0.f, 0.f, 0.f};
    float mrun = -INFINITY;          // per query (this lane's l15 column)
    float lrun = 0.f;
    const int q_idx = qt * 64 + w * 16 + l15;

    for (int kt = kt0; kt <= kt1; kt++) {
        __syncthreads();             // prior iter's sK/sVT readers done
        // stage this tile from prefetch regs
        *(uint4*)&sK[ro * LDP + co] = rK0;
        *(uint4*)&sK[(ro + 32) * LDP + co] = rK1;
        *(uint4*)&sVT[ro * LDP + co] = rV0;
        *(uint4*)&sVT[(ro + 32) * LDP + co] = rV1;
        // issue prefetch for next tile (clamped; redundant last-iter load is cheap)
        const int ktn = (kt < kt1) ? kt + 1 : kt;
        rK0 = *(const uint4*)(Kp + (size_t)(ktn * 64 + ro) * 64 + co);
        rK1 = *(const uint4*)(Kp + (size_t)(ktn * 64 + ro + 32) * 64 + co);
        rV0 = *(const uint4*)(Vp + (size_t)ro * 2048 + ktn * 64 + co);
        rV1 = *(const uint4*)(Vp + (size_t)(ro + 32) * 2048 + ktn * 64 + co);
        __syncthreads();

        // S^T tile: 64 keys x 16 queries per wave. A = K rows, B = Q^T.
        f32x4 sa[4];
#pragma unroll
        for (int i = 0; i < 4; i++) sa[i] = f32x4{0.f, 0.f, 0.f, 0.f};
#pragma unroll
        for (int ks = 0; ks < 2; ks++) {
#pragma unroll
            for (int ct = 0; ct < 4; ct++) {
                s16x8 kf = *(const s16x8*)&sK[(ct * 16 + l15) * LDP + ks * 32 + quad * 8];
                sa[ct] = MFMA16(kf, aq[ks], sa[ct]);
            }
        }

        float ps[4][4];
#pragma unroll
        for (int ct = 0; ct < 4; ct++)
#pragma unroll
            for (int r = 0; r < 4; r++) ps[ct][r] = sa[ct][r];

        if (kt == qt) {              // uniform branch: only the diagonal tile masks
#pragma unroll
            for (int ct = 0; ct < 4; ct++) {
                int kbase = kt * 64 + ct * 16 + quad * 4;
#pragma unroll
                for (int r = 0; r < 4; r++)
                    if ((kbase + r) > q_idx) ps[ct][r] = -INFINITY;
            }
        }

        // max over this query's keys: in-lane tree + cross-quad xor16/32
        float cm[4];
#pragma unroll
        for (int ct = 0; ct < 4; ct++)
            cm[ct] = fmaxf(fmaxf(ps[ct][0], ps[ct][1]), fmaxf(ps[ct][2], ps[ct][3]));
        float mx = fmaxf(fmaxf(cm[0], cm[1]), fmaxf(cm[2], cm[3]));
        mx = fmaxf(mx, __shfl_xor(mx, 16));
        mx = fmaxf(mx, __shfl_xor(mx, 32));
        float mnew = fmaxf(mrun, mx);
        float alpha = exp2f(mrun - mnew);
        mrun = mnew;
        float cs[4];
#pragma unroll
        for (int ct = 0; ct < 4; ct++) {
#pragma unroll
            for (int r = 0; r < 4; r++) ps[ct][r] = exp2f(ps[ct][r] - mnew);
            cs[ct] = (ps[ct][0] + ps[ct][1]) + (ps[ct][2] + ps[ct][3]);
        }
        float psum = (cs[0] + cs[1]) + (cs[2] + cs[3]);
        psum += __shfl_xor(psum, 16);
        psum += __shfl_xor(psum, 32);
        lrun = lrun * alpha + psum;

        // broadcast alpha (per query l15) to O rows (query quad*4+r)
        float arow[4];
#pragma unroll
        for (int r = 0; r < 4; r++) arow[r] = __shfl(alpha, quad * 4 + r);
#pragma unroll
        for (int ct = 0; ct < 4; ct++)
#pragma unroll
            for (int r = 0; r < 4; r++) o[ct][r] *= arow[r];

        // P^T (C-layout) -> sP rows = query, packed 4 keys per ds_write_b64
#pragma unroll
        for (int ct = 0; ct < 4; ct++) {
            unsigned lo = pack2t(ps[ct][0], ps[ct][1]);
            unsigned hi = pack2t(ps[ct][2], ps[ct][3]);
            *(uint2*)&sQP[(w * 16 + l15) * LDP + ct * 16 + quad * 4] = make_uint2(lo, hi);
        }
        // no barrier: rows are wave-private, same-wave DS ops in-order

        // O += P V  (A = P rows=query, B = V^T)
#pragma unroll
        for (int ks2 = 0; ks2 < 2; ks2++) {
            s16x8 pa = *(const s16x8*)&sQP[(w * 16 + l15) * LDP + ks2 * 32 + quad * 8];
#pragma unroll
            for (int ct = 0; ct < 4; ct++) {
                s16x8 vb = *(const s16x8*)&sVT[(ct * 16 + l15) * LDP + ks2 * 32 + quad * 8];
                o[ct] = MFMA16(pa, vb, o[ct]);
            }
        }
    }

    // epilogue: UNNORMALIZED partial O (bf16), m/l (fp32, per query row)
    const size_t pbase = ((size_t)(bh * 80 + u)) * 4096;
#pragma unroll
    for (int r = 0; r < 4; r++) {
        int row = w * 16 + quad * 4 + r;
#pragma unroll
        for (int ct = 0; ct < 4; ct++)
            paO[pbase + row * 64 + ct * 16 + l15] = f2bf(o[ct][r]);
    }
    if (quad == 0) {
        int mlbase = (bh * 80 + u) * 128;
        ml[mlbase + w * 16 + l15] = mrun;
        ml[mlbase + 64 + w * 16 + l15] = lrun;
    }
}

// ---------------------------------------------------------------------------
// Kernel 3b: combine partials. Block = (qt, bh); merges nch = qt/8+1 partials.
// ---------------------------------------------------------------------------
__global__ __launch_bounds__(256) void combine_kernel(
    const short* __restrict__ paO, const float* __restrict__ ml, short* __restrict__ Y) {
    const int qt = blockIdx.x, bh = blockIdx.y;
    const int b = bh >> 4, h = bh & 15;
    const int nch = (qt >> 3) + 1;
    int base;
    if (qt < 8) base = qt;
    else if (qt < 16) base = 8 + 2 * (qt - 8);
    else if (qt < 24) base = 24 + 3 * (qt - 16);
    else base = 48 + 4 * (qt - 24);

    const int row = threadIdx.x >> 2;
    const int cq = (threadIdx.x & 3) * 16;

    float mi[4], li[4];
    float M = -INFINITY;
    for (int i = 0; i < nch; i++) {
        int mlbase = (bh * 80 + base + i) * 128;
        mi[i] = ml[mlbase + row];
        li[i] = ml[mlbase + 64 + row];
        M = fmaxf(M, mi[i]);
    }
    float L = 0.f, ai[4];
    for (int i = 0; i < nch; i++) {
        ai[i] = exp2f(mi[i] - M);
        L += li[i] * ai[i];
    }
    const float inv = 1.0f / L;

    float acc[16];
#pragma unroll
    for (int j = 0; j < 16; j++) acc[j] = 0.f;
    for (int i = 0; i < nch; i++) {
        const short* p = paO + ((size_t)(bh * 80 + base + i)) * 4096 + row * 64 + cq;
        uint4 v0 = ((const uint4*)p)[0];
        uint4 v1 = ((const uint4*)p)[1];
        unsigned vs[8] = {v0.x, v0.y, v0.z, v0.w, v1.x, v1.y, v1.z, v1.w};
#pragma unroll
        for (int j = 0; j < 8; j++) {
            acc[2 * j + 0] += bf2f((short)(vs[j] & 0xFFFFu)) * ai[i];
            acc[2 * j + 1] += bf2f((short)(vs[j] >> 16)) * ai[i];
        }
    }
    const int t = qt * 64 + row;
    short* yp = Y + ((size_t)(b * 2048 + t)) * 1024 + h * 64 + cq;
    unsigned ow[8];
#pragma unroll
    for (int j = 0; j < 8; j++) ow[j] = pack2(acc[2 * j] * inv, acc[2 * j + 1] * inv);
    ((uint4*)yp)[0] = make_uint4(ow[0], ow[1], ow[2], ow[3]);
    ((uint4*)yp)[1] = make_uint4(ow[4], ow[5], ow[6], ow[7]);
}

// ---------------------------------------------------------------------------
// Kernel 4: output projection, 64x128 tiles -> grid (8,64)=512 blocks (2/CU,
// was 1/CU). Wave w owns a 64x32 output slab. fp32 out.
// ---------------------------------------------------------------------------
__global__ __launch_bounds__(256) void oproj_kernel(
    const short* __restrict__ Yb, const short* __restrict__ Wob, float* __restrict__ out) {
    __shared__ __align__(16) short sA[64 * 64];
    __shared__ __align__(16) short sB[128 * 64];
    const int tid = threadIdx.x;
    const int w = tid >> 6, lane = tid & 63, quad = lane >> 4, l15 = lane & 15;
    const int m0 = blockIdx.y * 64;
    const int nb = blockIdx.x * 128;

    f32x4 acc[4][2];
#pragma unroll
    for (int i = 0; i < 4; i++)
#pragma unroll
        for (int j = 0; j < 2; j++) acc[i][j] = f32x4{0.f, 0.f, 0.f, 0.f};

    for (int kb = 0; kb < 16; kb++) {
        const int k0 = kb * 64;
        if (kb) __syncthreads();
#pragma unroll
        for (int i = 0; i < 2; i++) {      // A: 64x64 shorts = 512 chunks
            int c = i * 256 + tid;
            int row = c >> 3, col8 = (c & 7) * 8;
            async_ld16(Yb + (size_t)(m0 + row) * 1024 + k0 + col8,
                       &sA[(i * 256 + w * 64) * 8]);
        }
#pragma unroll
        for (int i = 0; i < 4; i++) {      // B: 128x64 shorts = 1024 chunks
            int c = i * 256 + tid;
            int row = c >> 3, col8 = (c & 7) * 8;
            async_ld16(Wob + (size_t)(nb + row) * 1024 + k0 + col8,
                       &sB[(i * 256 + w * 64) * 8]);
        }
        __syncthreads();
#pragma unroll
        for (int ks = 0; ks < 2; ks++) {
            s16x8 av[4], bv[2];
#pragma unroll
            for (int at = 0; at < 4; at++)
                av[at] = *(const s16x8*)&sA[(at * 16 + l15) * 64 + ks * 32 + quad * 8];
#pragma unroll
            for (int bt = 0; bt < 2; bt++)
                bv[bt] = *(const s16x8*)&sB[(w * 32 + bt * 16 + l15) * 64 + ks * 32 + quad * 8];
#pragma unroll
            for (int at = 0; at < 4; at++)
#pragma unroll
                for (int bt = 0; bt < 2; bt++)
                    acc[at][bt] = MFMA16(av[at], bv[bt], acc[at][bt]);
        }
    }
#pragma unroll
    for (int at = 0; at < 4; at++)
#pragma unroll
        for (int r = 0; r < 4; r++) {
            int m = m0 + at * 16 + quad * 4 + r;
#pragma unroll
            for (int bt = 0; bt < 2; bt++) {
                int n = nb + w * 32 + bt * 16 + l15;
                out[(size_t)m * 1024 + n] = acc[at][bt][r];
            }
        }
}

extern "C" void kernel_launch(void* const* d_in, const int* in_sizes, int n_in,
                              void* d_out, int out_size, void* d_ws, size_t ws_size,
                              hipStream_t stream) {
    (void)in_sizes; (void)n_in; (void)out_size; (void)ws_size;
    const float* x  = (const float*)d_in[0];
    const float* Wq = (const float*)d_in[1];
    const float* Wk = (const float*)d_in[2];
    const float* Wv = (const float*)d_in[3];
    const float* Wo = (const float*)d_in[4];
    float* out = (float*)d_out;

    const size_t NE = (size_t)2 * 16 * 2048 * 64;   // 4M elems per tensor
    short* Q   = (short*)d_ws;
    short* K   = Q + NE;
    short* VT  = K + NE;          // [B,H,D,T]
    short* Y   = VT + NE;         // attn output [B,T,C] bf16
    short* xb  = Y;               // x bf16 ALIASES Y: consumed by qkv before combine writes Y
    short* wb  = Y + NE;          // [Wq|Wk|Wv|Wo] bf16, 4M elems
    short* paO = wb + NE;         // partial O: 32 bh x 80 units x 64x64 bf16 = 21 MB
    float* ml  = (float*)(paO + (size_t)32 * 80 * 4096);   // m,l: 32x80x128 fp32

    convert_kernel<<<4096, 256, 0, stream>>>(x, Wq, Wk, Wv, Wo, xb, wb);
    qkv_kernel<<<dim3(24, 32), 256, 0, stream>>>(xb, wb, Q, K, VT);
    rope_kernel<<<512, 256, 0, stream>>>(Q, K);
    attn_kernel<<<dim3(80, 32), 256, 0, stream>>>(Q, K, VT, paO, ml);
    combine_kernel<<<dim3(32, 32), 256, 0, stream>>>(paO, ml, Y);
    oproj_kernel<<<dim3(8, 64), 256, 0, stream>>>(Y, wb + 3 * 1048576, out);
}